// Round 16
// baseline (523.590 us; speedup 1.0000x reference)
//
#include <hip/hip_runtime.h>
#include <math.h>

typedef __attribute__((ext_vector_type(4))) float f32x4;
typedef __attribute__((ext_vector_type(8))) _Float16 f16x8;

__device__ __forceinline__ f32x4 mfma16h(f16x8 a, f16x8 b, f32x4 c){
  return __builtin_amdgcn_mfma_f32_16x16x32_f16(a, b, c, 0, 0, 0);
}
__device__ __forceinline__ void gload_lds16(const void* g, void* l){
  __builtin_amdgcn_global_load_lds((const __attribute__((address_space(1))) void*)g,
                                   (__attribute__((address_space(3))) void*)l, 16, 0, 0);
}

#define EXPC 0.1803368801111204f   // 0.125 * log2(e)
// global K swizzle phi(n) = bits (n3,n1,n0): chosen so phi(kappa(p)) = p&7 ->
// attn K-read XOR is (r16&7)*8, sequential across lanes = conflict-free (r10-verified).
#define PHI(n) (((((n)>>3)&1)<<2) | ((((n)>>1)&1)<<1) | ((n)&1))

// ---------------- weight stats: alpha=mean(w), beta-sum=sum|w| ----------------
__global__ __launch_bounds__(256) void k_wstats(const float* __restrict__ w1, const float* __restrict__ w2,
                                                double* __restrict__ dsum, double* __restrict__ dabs){
  const int mat = blockIdx.y;
  const float* wp = (mat < 6) ? (w1 + (size_t)mat*1048576) : (w2 + (size_t)(mat-6)*1048576);
  const f32x4* wv = (const f32x4*)wp + (size_t)blockIdx.x*8192;
  double s = 0.0, a = 0.0;
  for (int j = 0; j < 32; j++){
    f32x4 v = wv[j*256 + threadIdx.x];
    s += (double)v.x + (double)v.y + (double)v.z + (double)v.w;
    a += (double)fabsf(v.x) + (double)fabsf(v.y) + (double)fabsf(v.z) + (double)fabsf(v.w);
  }
  for (int d = 1; d < 64; d <<= 1){ s += __shfl_xor(s, d); a += __shfl_xor(a, d); }
  __shared__ double red[8];
  const int w = threadIdx.x >> 6;
  if ((threadIdx.x & 63) == 0){ red[w*2] = s; red[w*2+1] = a; }
  __syncthreads();
  if (threadIdx.x == 0){
    double S = red[0]+red[2]+red[4]+red[6], A = red[1]+red[3]+red[5]+red[7];
    atomicAdd(&dsum[mat], S);
    atomicAdd(&dabs[mat], A);
  }
}

// ---------------- binarize weights to fp16 {-1,0,+1}, swizzled GEMM-B layout ----------------
// layout: wb[mat][n][ (k&~63) + ((k&63) ^ 8*(n&7)) ]
__global__ __launch_bounds__(256) void k_binarize(const float* __restrict__ w1, const float* __restrict__ w2,
                                                  const double* __restrict__ dsum, _Float16* __restrict__ wb){
  const int blk = blockIdx.x;          // 6144 blocks, 512 per matrix
  const int mat = blk >> 9;
  const float alpha = (float)(dsum[mat] * (1.0/1048576.0));
  const float* wp = (mat < 6) ? (w1 + (size_t)mat*1048576) : (w2 + (size_t)(mat-6)*1048576);
  const size_t off = (size_t)(blk & 511)*2048 + (size_t)threadIdx.x*8;
  const int n = (int)(off >> 10), k = (int)(off & 1023);
  f32x4 v0 = *(const f32x4*)(wp + off), v1 = *(const f32x4*)(wp + off + 4);
  float vv[8] = {v0.x,v0.y,v0.z,v0.w,v1.x,v1.y,v1.z,v1.w};
  f16x8 pk;
  #pragma unroll
  for (int e = 0; e < 8; e++){
    float d = vv[e] - alpha;
    pk[e] = d > 0.f ? (_Float16)1.0f : (d < 0.f ? (_Float16)(-1.0f) : (_Float16)0.0f);
  }
  const size_t addr = (size_t)mat*1048576 + (size_t)n*1024 + (size_t)((k & ~63) + ((k & 63) ^ ((n&7)*8)));
  *(f16x8*)&wb[addr] = pk;
}

// ---------------- presplit (layer 0 only): x -> fp16 hi/lo K-layout + V^T-layout ----------------
// K:  Kh/Kl[bh][n][ d ^ 8*PHI(n&63) ]
// VT: Vh/Vl[bh][d][ t*64 + ((n&63) ^ 8*(d&7)) ]
__global__ __launch_bounds__(256) void k_presplit(const float* __restrict__ x,
                                                  _Float16* __restrict__ Kh, _Float16* __restrict__ Kl,
                                                  _Float16* __restrict__ Vh, _Float16* __restrict__ Vl){
  __shared__ _Float16 lh[64*72], ll[64*72];
  const int t = blockIdx.x, bh = blockIdx.y, b = bh>>4, h = bh&15;
  const int n = threadIdx.x>>2, c0 = (threadIdx.x&3)*16;
  const float* src = x + (size_t)b*1048576 + (size_t)(t*64+n)*1024 + h*64 + c0;
  const size_t kbase = ((size_t)bh*1024 + t*64 + n)*64;
  const int sw = PHI(n)*8;
  #pragma unroll
  for (int j = 0; j < 2; j++){
    f32x4 v0 = *(const f32x4*)(src + j*8);
    f32x4 v1 = *(const f32x4*)(src + j*8 + 4);
    float vv[8] = {v0.x,v0.y,v0.z,v0.w,v1.x,v1.y,v1.z,v1.w};
    f16x8 Hv, Lv;
    #pragma unroll
    for (int e = 0; e < 8; e++){
      _Float16 hh = (_Float16)vv[e];
      Hv[e] = hh; Lv[e] = (_Float16)(vv[e] - (float)hh);
      const int d = c0 + j*8 + e;
      lh[d*72 + n] = Hv[e]; ll[d*72 + n] = Lv[e];
    }
    const int db = c0 + j*8;
    *(f16x8*)&Kh[kbase + (db ^ sw)] = Hv;
    *(f16x8*)&Kl[kbase + (db ^ sw)] = Lv;
  }
  __syncthreads();
  const int d = threadIdx.x>>2, n0c = (threadIdx.x&3)*16;
  const size_t vbase = ((size_t)bh*64 + d)*1024 + t*64;
  const int sw2 = (d&7)*8;
  #pragma unroll
  for (int j = 0; j < 2; j++){
    const int nb = n0c + j*8;
    *(f16x8*)&Vh[vbase + (nb ^ sw2)] = *(const f16x8*)&lh[d*72 + nb];
    *(f16x8*)&Vl[vbase + (nb ^ sw2)] = *(const f16x8*)&ll[d*72 + nb];
  }
}

// ---------------- flash attention + residual: swapped QK^T, S-pipeline (r12/r15) ----------------
// grid (32 bh, 16 qt), 256 thr, 2 blocks/CU.
__global__ __launch_bounds__(256) void k_attn(const _Float16* __restrict__ Kh, const _Float16* __restrict__ Kl,
                                              const _Float16* __restrict__ Vh, const _Float16* __restrict__ Vl,
                                              const float* __restrict__ xin, float* __restrict__ xout){
  __shared__ _Float16 smb[40960];   // 80 KB: K0,K1,K2 (8192 el each) + V0,V1 (8192 el each)
  const int tid = threadIdx.x, w = tid>>6, l = tid&63, g = l>>4, r16 = l&15;
  const int bh = blockIdx.x, qt = blockIdx.y, b = bh>>4, h = bh&15;
  const _Float16* Kbh = Kh + (size_t)bh*65536;
  const _Float16* Kbl = Kl + (size_t)bh*65536;

  size_t koffK[2], voff[2];
  int cbj[2];
  #pragma unroll
  for (int j = 0; j < 2; j++){
    const int cb = (j*4 + w)*64, c = cb + l;
    const int p  = c>>3;
    const int kp = (p&32) | ((p&12)<<1) | ((p&16)>>2) | (p&3);   // kappa(p)
    cbj[j]   = cb;
    koffK[j] = (size_t)kp*64 + (size_t)(l&7)*8;
    voff[j]  = ((size_t)bh*64 + (c>>3))*1024 + (size_t)(c&7)*8;
  }
  #define KSTAGE(PK, T) { _Pragma("unroll")                                          \
    for (int j = 0; j < 2; j++){                                                      \
      gload_lds16(Kbh + (size_t)(T)*4096 + koffK[j], (PK) + cbj[j]*8);                \
      gload_lds16(Kbl + (size_t)(T)*4096 + koffK[j], (PK) + 4096 + cbj[j]*8);         \
    } }
  #define VSTAGE(PV, T) { _Pragma("unroll")                                          \
    for (int j = 0; j < 2; j++){                                                      \
      gload_lds16(Vh + voff[j] + (T)*64, (PV) + cbj[j]*8);                            \
      gload_lds16(Vl + voff[j] + (T)*64, (PV) + 4096 + cbj[j]*8);                     \
    } }

  _Float16* pKo = smb;
  _Float16* pKn = smb + 8192;
  _Float16* pKs = smb + 16384;
  _Float16* pVc = smb + 24576;
  _Float16* pVs = smb + 32768;

  KSTAGE(pKo, 0); KSTAGE(pKn, 1); VSTAGE(pVc, 0);
  const int qrow = w*16 + r16;
  const int phq8 = PHI(qrow)*8;
  const size_t qb = (size_t)qt*4096 + (size_t)qrow*64;
  const f16x8 aqh0 = *(const f16x8*)&Kbh[qb + ((g*8) ^ phq8)];
  const f16x8 aqh1 = *(const f16x8*)&Kbh[qb + ((32 + g*8) ^ phq8)];
  const f16x8 aql0 = *(const f16x8*)&Kbl[qb + ((g*8) ^ phq8)];
  const f16x8 aql1 = *(const f16x8*)&Kbl[qb + ((32 + g*8) ^ phq8)];
  __syncthreads();

  const int swk8 = (r16&7)*8;
  float mI = -1e30f, lI = 0.f;
  f32x4 acc[4], sA[4], sB[4];
  #pragma unroll
  for (int i = 0; i < 4; i++) acc[i] = (f32x4){0.f,0.f,0.f,0.f};

  #define QKT(PK, SD) { const _Float16* kt_h = (PK); const _Float16* kt_l = (PK) + 4096;  \
    _Pragma("unroll")                                                                      \
    for (int c = 0; c < 4; c++){                                                           \
      const int rk = c*16 + r16;                                                           \
      const f16x8 kh0 = *(const f16x8*)&kt_h[rk*64 + ((g*8) ^ swk8)];                      \
      const f16x8 kh1 = *(const f16x8*)&kt_h[rk*64 + ((32+g*8) ^ swk8)];                   \
      const f16x8 kl0 = *(const f16x8*)&kt_l[rk*64 + ((g*8) ^ swk8)];                      \
      const f16x8 kl1 = *(const f16x8*)&kt_l[rk*64 + ((32+g*8) ^ swk8)];                   \
      f32x4 z = (f32x4){0.f,0.f,0.f,0.f};                                                  \
      z = mfma16h(kh0, aqh0, z);                                                           \
      z = mfma16h(kh1, aqh1, z);                                                           \
      z = mfma16h(kh0, aql0, z);                                                           \
      z = mfma16h(kh1, aql1, z);                                                           \
      z = mfma16h(kl0, aqh0, z);                                                           \
      z = mfma16h(kl1, aqh1, z);                                                           \
      (SD)[c] = z;                                                                         \
    } }

  #define SMAXPV(SC) {                                                                     \
    float rmax = (SC)[0][0];                                                               \
    _Pragma("unroll")                                                                      \
    for (int c = 0; c < 4; c++)                                                            \
      _Pragma("unroll")                                                                    \
      for (int i = 0; i < 4; i++) rmax = fmaxf(rmax, (SC)[c][i]);                          \
    rmax = fmaxf(rmax, __shfl_xor(rmax, 16));                                              \
    rmax = fmaxf(rmax, __shfl_xor(rmax, 32));                                              \
    if (__any(rmax - mI > 44.36f)){                                                        \
      const float mn = fmaxf(mI, rmax);                                                    \
      const float fac = exp2f((mI - mn)*EXPC);                                             \
      lI *= fac;                                                                           \
      mI = mn;                                                                             \
      _Pragma("unroll")                                                                    \
      for (int i = 0; i < 4; i++){                                                         \
        const float fi = __shfl(fac, g*4 + i);                                             \
        _Pragma("unroll")                                                                  \
        for (int dc = 0; dc < 4; dc++) acc[dc][i] *= fi;                                   \
      }                                                                                    \
    }                                                                                      \
    const float mC = mI*EXPC;                                                              \
    float rsum = 0.f;                                                                      \
    f16x8 aph[2], apl[2];                                                                  \
    _Pragma("unroll")                                                                      \
    for (int c = 0; c < 4; c++)                                                            \
      _Pragma("unroll")                                                                    \
      for (int i = 0; i < 4; i++){                                                         \
        const float p = exp2f(fmaf((SC)[c][i], EXPC, -mC));                                \
        const _Float16 ph = (_Float16)p;                                                   \
        aph[c>>1][(c&1)*4 + i] = ph;                                                       \
        apl[c>>1][(c&1)*4 + i] = (_Float16)(p - (float)ph);                                \
        rsum += p;                                                                         \
      }                                                                                    \
    rsum += __shfl_xor(rsum, 16);                                                          \
    rsum += __shfl_xor(rsum, 32);                                                          \
    lI += rsum;                                                                            \
    const _Float16* vt_h = pVc; const _Float16* vt_l = pVc + 4096;                         \
    _Pragma("unroll")                                                                      \
    for (int ks = 0; ks < 2; ks++){                                                        \
      _Pragma("unroll")                                                                    \
      for (int dc = 0; dc < 4; dc++){                                                      \
        const int vr = dc*16 + r16;                                                        \
        const f16x8 bvh = *(const f16x8*)&vt_h[vr*64 + ((ks*32 + g*8) ^ swk8)];            \
        const f16x8 bvl = *(const f16x8*)&vt_l[vr*64 + ((ks*32 + g*8) ^ swk8)];            \
        acc[dc] = mfma16h(aph[ks], bvh, acc[dc]);                                          \
        acc[dc] = mfma16h(apl[ks], bvh, acc[dc]);                                          \
        acc[dc] = mfma16h(aph[ks], bvl, acc[dc]);                                          \
      }                                                                                    \
    } }

  QKT(pKo, sA);

  for (int tt = 0; tt < 8; tt++){
    {
      const int t = 2*tt;
      if (t < 14) KSTAGE(pKs, t+2);
      VSTAGE(pVs, t+1);
      QKT(pKn, sB);
      SMAXPV(sA);
      __syncthreads();
      _Float16* tk = pKo; pKo = pKn; pKn = pKs; pKs = tk;
      _Float16* tv = pVc; pVc = pVs; pVs = tv;
    }
    {
      const int t = 2*tt+1;
      if (t < 14) KSTAGE(pKs, t+2);
      if (t < 15) VSTAGE(pVs, t+1);
      if (t < 15) QKT(pKn, sA);
      SMAXPV(sB);
      __syncthreads();
      _Float16* tk = pKo; pKo = pKn; pKn = pKs; pKs = tk;
      _Float16* tv = pVc; pVc = pVs; pVs = tv;
    }
  }
  #undef KSTAGE
  #undef VSTAGE
  #undef QKT
  #undef SMAXPV

  #pragma unroll
  for (int i = 0; i < 4; i++){
    const float li = __shfl(lI, g*4 + i);
    const float inv = 1.f/li;
    const int row = qt*64 + w*16 + g*4 + i;
    #pragma unroll
    for (int dc = 0; dc < 4; dc++){
      const size_t idx = (size_t)b*1048576 + (size_t)row*1024 + h*64 + dc*16 + r16;
      xout[idx] = acc[dc][i]*inv + xin[idx];
    }
  }
}

// ---------------- layernorm; SPLIT=1 writes fp16 hi/lo in swizzled A-layout ----------------
template<int SPLIT>
__global__ __launch_bounds__(256) void k_ln(const float* __restrict__ x, const float* __restrict__ gg,
                                            const float* __restrict__ bb, float* __restrict__ outf,
                                            _Float16* __restrict__ Oh, _Float16* __restrict__ Ol){
  const int row = blockIdx.x*4 + (threadIdx.x>>6);
  const int lane = threadIdx.x & 63;
  const float* xr = x + (size_t)row*1024;
  f32x4 v[4];
  float s = 0.f, q = 0.f;
  #pragma unroll
  for (int c = 0; c < 2; c++){
    v[c*2]   = *(const f32x4*)(xr + c*512 + lane*8);
    v[c*2+1] = *(const f32x4*)(xr + c*512 + lane*8 + 4);
    #pragma unroll
    for (int e = 0; e < 4; e++){
      s += v[c*2][e] + v[c*2+1][e];
      q += v[c*2][e]*v[c*2][e] + v[c*2+1][e]*v[c*2+1][e];
    }
  }
  for (int d = 1; d < 64; d <<= 1){ s += __shfl_xor(s,d); q += __shfl_xor(q,d); }
  const float mean = s * (1.f/1024.f);
  const float var  = q * (1.f/1024.f) - mean*mean;
  const float rstd = rsqrtf(var + 1e-5f);
  #pragma unroll
  for (int c = 0; c < 2; c++){
    const int col = c*512 + lane*8;
    f32x4 g0 = *(const f32x4*)(gg + col), g1 = *(const f32x4*)(gg + col + 4);
    f32x4 b0 = *(const f32x4*)(bb + col), b1 = *(const f32x4*)(bb + col + 4);
    float h[8];
    #pragma unroll
    for (int e = 0; e < 4; e++){
      h[e]   = (v[c*2][e]  -mean)*rstd*g0[e] + b0[e];
      h[e+4] = (v[c*2+1][e]-mean)*rstd*g1[e] + b1[e];
    }
    if (SPLIT){
      f16x8 Hv, Lv;
      #pragma unroll
      for (int e = 0; e < 8; e++){
        _Float16 hh = (_Float16)h[e];
        Hv[e] = hh; Lv[e] = (_Float16)(h[e] - (float)hh);
      }
      const size_t addr = (size_t)row*1024 + c*512 + (lane>>3)*64 + (((lane&7)*8) ^ ((row&7)*8));
      *(f16x8*)&Oh[addr] = Hv;
      *(f16x8*)&Ol[addr] = Lv;
    } else {
      f32x4 o0, o1;
      #pragma unroll
      for (int e = 0; e < 4; e++){ o0[e] = h[e]; o1[e] = h[e+4]; }
      *(f32x4*)(outf + (size_t)row*1024 + col) = o0;
      *(f32x4*)(outf + (size_t)row*1024 + col + 4) = o1;
    }
  }
}

// ---------------- bitlinear GEMM: C[2048,1024] = (Ah+Al).Wb^T * beta ----------------
// BM=32, BN=64, BK=64, grid (16,64) = 1024 blocks. T3/T4: 3-buffer deep pipeline with
// COUNTED vmcnt (never 0 in steady state) + raw s_barrier -- no per-tile vmcnt(0) drain.
// Schedule per tile t: { vmcnt(4) [retires stage(t); stage(t+1) stays in flight] ->
// s_barrier -> compute(t) -> issue stage(t+2) into buf (t+2)%3 }. Race-safe: buf(t+2)%3
// = buf(t-1)%3 whose readers all passed this iter's barrier. LDS 48KB -> 3 blocks/CU.
// Arithmetic identical to r15 -> bit-identical output.
// MODE 0: GELU -> split fp16 out (swizzled A-layout).
// MODE 1: += into fp32 residual; if Kh!=null, ALSO produce next layer's K/V splits
//         (block == half of a presplit unit: tseq=by>>1&15, half=by&1, head=bx).
template<int MODE>
__global__ __launch_bounds__(256) void k_gemm(const _Float16* __restrict__ Ah, const _Float16* __restrict__ Al,
                                              const _Float16* __restrict__ Wg,
                                              float* __restrict__ out32,
                                              _Float16* __restrict__ Oh, _Float16* __restrict__ Ol,
                                              const double* __restrict__ dabs_slot,
                                              _Float16* __restrict__ Kh, _Float16* __restrict__ Kl,
                                              _Float16* __restrict__ Vh, _Float16* __restrict__ Vl){
  __shared__ _Float16 smb[24576];   // 48KB: 3 x (A-hi 2048 + A-lo 2048 + B 4096); reused post-loop
  const int tid = threadIdx.x, w = tid>>6, l = tid&63, g = l>>4, r16 = l&15;
  const int wm = w>>1, wn = w&1;
  const int n0 = blockIdx.x*64, m0 = blockIdx.y*32;
  const float scale = (float)(*dabs_slot * (1.0/1048576.0));
  const int swr = (r16&7)*8;
  f32x4 acc[2] = {};
  // staging: A-hi 4KB (wave w -> rows w*8..+7), A-lo 4KB, B 8KB (chunks j*4+w)
  #define STAGE(buf, k0) { _Float16* Bp = smb + (buf)*8192;                               \
    gload_lds16(Ah + (size_t)(m0 + w*8 + (l>>3))*1024 + (k0) + (l&7)*8, Bp + w*512);      \
    gload_lds16(Al + (size_t)(m0 + w*8 + (l>>3))*1024 + (k0) + (l&7)*8, Bp + 2048 + w*512);\
    _Pragma("unroll")                                                                     \
    for (int j = 0; j < 2; j++){                                                          \
      const int ch = j*4 + w;                                                             \
      gload_lds16(Wg + (size_t)(n0 + ch*8 + (l>>3))*1024 + (k0) + (l&7)*8,                \
                  Bp + 4096 + ch*512);                                                    \
    } }
  STAGE(0, 0);
  STAGE(1, 64);
  #pragma unroll
  for (int t = 0; t < 16; t++){
    if (t < 15){ asm volatile("s_waitcnt vmcnt(4)" ::: "memory"); }
    else       { asm volatile("s_waitcnt vmcnt(0)" ::: "memory"); }
    __builtin_amdgcn_s_barrier();
    asm volatile("" ::: "memory");
    const _Float16* Bp = smb + (t % 3)*8192;
    #pragma unroll
    for (int kk = 0; kk < 2; kk++){
      const int col = (kk*32 + g*8) ^ swr;
      const int arow = wm*16 + r16;
      const f16x8 ah = *(const f16x8*)&Bp[arow*64 + col];
      const f16x8 al = *(const f16x8*)&Bp[2048 + arow*64 + col];
      const f16x8 bf0 = *(const f16x8*)&Bp[4096 + (wn*32 + r16)*64 + col];
      const f16x8 bf1 = *(const f16x8*)&Bp[4096 + (wn*32 + 16 + r16)*64 + col];
      acc[0] = mfma16h(ah, bf0, acc[0]);
      acc[0] = mfma16h(al, bf0, acc[0]);
      acc[1] = mfma16h(ah, bf1, acc[1]);
      acc[1] = mfma16h(al, bf1, acc[1]);
    }
    if (t < 14) STAGE((t+2) % 3, (t+2)*64);
  }
  #undef STAGE
  __syncthreads();   // all waves done with tile 15 before LDS reuse below
  // post-loop LDS reuse: split-tile staging for fused KV
  _Float16* kh_t = smb;            // [32][72] token-major hi
  _Float16* kl_t = smb + 2304;     // [32][72] token-major lo
  _Float16* lhv  = smb + 4608;     // [64][40] d-major hi (32 token cols)
  _Float16* llv  = smb + 7168;     // [64][40] d-major lo
  #pragma unroll
  for (int ni = 0; ni < 2; ni++)
    #pragma unroll
    for (int i = 0; i < 4; i++){
      const int rr = m0 + wm*16 + g*4 + i;
      const int cc = n0 + wn*32 + ni*16 + r16;
      float vv = acc[ni][i] * scale;
      if (MODE == 0){
        vv = 0.5f*vv*(1.f + erff(vv*0.70710678118f));
        _Float16 hh = (_Float16)vv;
        const size_t addr = (size_t)rr*1024 + (cc & ~63) + ((cc & 63) ^ ((rr&7)*8));
        Oh[addr] = hh;
        Ol[addr] = (_Float16)(vv - (float)hh);
      } else {
        const size_t idx = (size_t)rr*1024 + cc;
        const float xnew = out32[idx] + vv;
        out32[idx] = xnew;
        if (Kh){
          const int nl = wm*16 + g*4 + i;          // token within 32-tile
          const int dl = wn*32 + ni*16 + r16;      // d within head
          const _Float16 hh = (_Float16)xnew;
          const _Float16 lo = (_Float16)(xnew - (float)hh);
          kh_t[nl*72 + dl] = hh;  kl_t[nl*72 + dl] = lo;
          lhv [dl*40 + nl] = hh;  llv [dl*40 + nl] = lo;
        }
      }
    }
  if (MODE == 1 && Kh){
    __syncthreads();
    const int bh2  = (blockIdx.y>>5)*16 + blockIdx.x;   // batch*16 + head
    const int tseq = (blockIdx.y>>1) & 15;              // 64-token KV tile
    const int half = blockIdx.y & 1;                    // which 32-token half
    // K: 32 rows x 64 d, one f16x8 per thread per buffer
    const int n = tid>>3, c0q = (tid&7)*8;
    const size_t kbase = ((size_t)bh2*1024 + tseq*64 + half*32 + n)*64;
    const int swn = PHI(n)*8;    // PHI reads bits 3,1,0 only -> half-offset transparent
    *(f16x8*)&Kh[kbase + (c0q ^ swn)] = *(const f16x8*)&kh_t[n*72 + c0q];
    *(f16x8*)&Kl[kbase + (c0q ^ swn)] = *(const f16x8*)&kl_t[n*72 + c0q];
    // V: 64 d x 32 token-cols, one f16x8 per thread per buffer
    const int d = tid>>2, lb = (tid&3)*8;
    const size_t vbase = ((size_t)bh2*64 + d)*1024 + tseq*64;
    const int sw2 = (d&7)*8;
    const int colw = (half*32 + lb) ^ sw2;   // 8-aligned (sw2 only touches bits 3..5)
    *(f16x8*)&Vh[vbase + colw] = *(const f16x8*)&lhv[d*40 + lb];
    *(f16x8*)&Vl[vbase + colw] = *(const f16x8*)&llv[d*40 + lb];
  }
}

extern "C" void kernel_launch(void* const* d_in, const int* in_sizes, int n_in,
                              void* d_out, int out_size, void* d_ws, size_t ws_size,
                              hipStream_t stream){
  const float* x_in = (const float*)d_in[0];
  const float* ln_g = (const float*)d_in[1];
  const float* ln_b = (const float*)d_in[2];
  const float* w1   = (const float*)d_in[3];
  const float* w2   = (const float*)d_in[4];
  const float* fg   = (const float*)d_in[5];
  const float* fb   = (const float*)d_in[6];

  char* ws = (char*)d_ws;
  double*   dsum  = (double*)ws;            // 12
  double*   dabs  = (double*)(ws + 96);     // 12
  _Float16* wb = (_Float16*)(ws + 256);     // 12 * 1M fp16 = 24 MB
  size_t o = 256 + 12ull*1048576ull*2ull;
  float* xA = (float*)(ws + o); o += 2048ull*1024*4;
  float* xB = (float*)(ws + o); o += 2048ull*1024*4;
  _Float16* Kh = (_Float16*)(ws + o); o += 2048ull*1024*2;
  _Float16* Kl = (_Float16*)(ws + o); o += 2048ull*1024*2;
  _Float16* Vh = (_Float16*)(ws + o); o += 2048ull*1024*2;
  _Float16* Vl = (_Float16*)(ws + o); o += 2048ull*1024*2;
  _Float16* Ahb = (_Float16*)(ws + o); o += 2048ull*1024*2;
  _Float16* Alb = (_Float16*)(ws + o); o += 2048ull*1024*2;
  _Float16* Ghb = (_Float16*)(ws + o); o += 2048ull*1024*2;
  _Float16* Glb = (_Float16*)(ws + o); o += 2048ull*1024*2;

  hipMemsetAsync(ws, 0, 256, stream);
  k_wstats  <<<dim3(32,12), 256, 0, stream>>>(w1, w2, dsum, dabs);
  k_binarize<<<6144,        256, 0, stream>>>(w1, w2, dsum, wb);
  k_presplit<<<dim3(16,32), 256, 0, stream>>>(x_in, Kh, Kl, Vh, Vl);

  const float* xc = x_in;
  for (int i = 0; i < 6; i++){
    float* xn = (i & 1) ? xB : xA;
    const bool last = (i == 5);
    k_attn    <<<dim3(32,16), 256, 0, stream>>>(Kh, Kl, Vh, Vl, xc, xn);
    k_ln<1>   <<<512, 256, 0, stream>>>(xn, ln_g + (size_t)i*1024, ln_b + (size_t)i*1024,
                                        nullptr, Ahb, Alb);
    k_gemm<0> <<<dim3(16,64), 256, 0, stream>>>(Ahb, Alb, wb + (size_t)i*1048576,
                                                nullptr, Ghb, Glb, &dabs[i],
                                                nullptr, nullptr, nullptr, nullptr);
    k_gemm<1> <<<dim3(16,64), 256, 0, stream>>>(Ghb, Glb, wb + (size_t)(6+i)*1048576,
                                                xn, nullptr, nullptr, &dabs[6+i],
                                                last ? nullptr : Kh, last ? nullptr : Kl,
                                                last ? nullptr : Vh, last ? nullptr : Vl);
    xc = xn;
  }
  k_ln<0><<<512, 256, 0, stream>>>(xc, fg, fb, (float*)d_out, nullptr, nullptr);
}

// Round 17
// 504.014 us; speedup vs baseline: 1.0388x; 1.0388x over previous
//
#include <hip/hip_runtime.h>
#include <math.h>

typedef __attribute__((ext_vector_type(4))) float f32x4;
typedef __attribute__((ext_vector_type(8))) _Float16 f16x8;

__device__ __forceinline__ f32x4 mfma16h(f16x8 a, f16x8 b, f32x4 c){
  return __builtin_amdgcn_mfma_f32_16x16x32_f16(a, b, c, 0, 0, 0);
}
__device__ __forceinline__ void gload_lds16(const void* g, void* l){
  __builtin_amdgcn_global_load_lds((const __attribute__((address_space(1))) void*)g,
                                   (__attribute__((address_space(3))) void*)l, 16, 0, 0);
}

#define EXPC 0.1803368801111204f   // 0.125 * log2(e)
// global K swizzle phi(n) = bits (n3,n1,n0): chosen so phi(kappa(p)) = p&7 ->
// attn K-read XOR is (r16&7)*8, sequential across lanes = conflict-free (r10-verified).
#define PHI(n) (((((n)>>3)&1)<<2) | ((((n)>>1)&1)<<1) | ((n)&1))

// ---------------- weight stats: alpha=mean(w), beta-sum=sum|w| ----------------
__global__ __launch_bounds__(256) void k_wstats(const float* __restrict__ w1, const float* __restrict__ w2,
                                                double* __restrict__ dsum, double* __restrict__ dabs){
  const int mat = blockIdx.y;
  const float* wp = (mat < 6) ? (w1 + (size_t)mat*1048576) : (w2 + (size_t)(mat-6)*1048576);
  const f32x4* wv = (const f32x4*)wp + (size_t)blockIdx.x*8192;
  double s = 0.0, a = 0.0;
  for (int j = 0; j < 32; j++){
    f32x4 v = wv[j*256 + threadIdx.x];
    s += (double)v.x + (double)v.y + (double)v.z + (double)v.w;
    a += (double)fabsf(v.x) + (double)fabsf(v.y) + (double)fabsf(v.z) + (double)fabsf(v.w);
  }
  for (int d = 1; d < 64; d <<= 1){ s += __shfl_xor(s, d); a += __shfl_xor(a, d); }
  __shared__ double red[8];
  const int w = threadIdx.x >> 6;
  if ((threadIdx.x & 63) == 0){ red[w*2] = s; red[w*2+1] = a; }
  __syncthreads();
  if (threadIdx.x == 0){
    double S = red[0]+red[2]+red[4]+red[6], A = red[1]+red[3]+red[5]+red[7];
    atomicAdd(&dsum[mat], S);
    atomicAdd(&dabs[mat], A);
  }
}

// ---------------- binarize weights to fp16 {-1,0,+1}, swizzled GEMM-B layout ----------------
// layout: wb[mat][n][ (k&~63) + ((k&63) ^ 8*(n&7)) ]
__global__ __launch_bounds__(256) void k_binarize(const float* __restrict__ w1, const float* __restrict__ w2,
                                                  const double* __restrict__ dsum, _Float16* __restrict__ wb){
  const int blk = blockIdx.x;          // 6144 blocks, 512 per matrix
  const int mat = blk >> 9;
  const float alpha = (float)(dsum[mat] * (1.0/1048576.0));
  const float* wp = (mat < 6) ? (w1 + (size_t)mat*1048576) : (w2 + (size_t)(mat-6)*1048576);
  const size_t off = (size_t)(blk & 511)*2048 + (size_t)threadIdx.x*8;
  const int n = (int)(off >> 10), k = (int)(off & 1023);
  f32x4 v0 = *(const f32x4*)(wp + off), v1 = *(const f32x4*)(wp + off + 4);
  float vv[8] = {v0.x,v0.y,v0.z,v0.w,v1.x,v1.y,v1.z,v1.w};
  f16x8 pk;
  #pragma unroll
  for (int e = 0; e < 8; e++){
    float d = vv[e] - alpha;
    pk[e] = d > 0.f ? (_Float16)1.0f : (d < 0.f ? (_Float16)(-1.0f) : (_Float16)0.0f);
  }
  const size_t addr = (size_t)mat*1048576 + (size_t)n*1024 + (size_t)((k & ~63) + ((k & 63) ^ ((n&7)*8)));
  *(f16x8*)&wb[addr] = pk;
}

// ---------------- presplit (layer 0 only): x -> fp16 hi/lo K-layout + V^T-layout ----------------
// K:  Kh/Kl[bh][n][ d ^ 8*PHI(n&63) ]
// VT: Vh/Vl[bh][d][ t*64 + ((n&63) ^ 8*(d&7)) ]
__global__ __launch_bounds__(256) void k_presplit(const float* __restrict__ x,
                                                  _Float16* __restrict__ Kh, _Float16* __restrict__ Kl,
                                                  _Float16* __restrict__ Vh, _Float16* __restrict__ Vl){
  __shared__ _Float16 lh[64*72], ll[64*72];
  const int t = blockIdx.x, bh = blockIdx.y, b = bh>>4, h = bh&15;
  const int n = threadIdx.x>>2, c0 = (threadIdx.x&3)*16;
  const float* src = x + (size_t)b*1048576 + (size_t)(t*64+n)*1024 + h*64 + c0;
  const size_t kbase = ((size_t)bh*1024 + t*64 + n)*64;
  const int sw = PHI(n)*8;
  #pragma unroll
  for (int j = 0; j < 2; j++){
    f32x4 v0 = *(const f32x4*)(src + j*8);
    f32x4 v1 = *(const f32x4*)(src + j*8 + 4);
    float vv[8] = {v0.x,v0.y,v0.z,v0.w,v1.x,v1.y,v1.z,v1.w};
    f16x8 Hv, Lv;
    #pragma unroll
    for (int e = 0; e < 8; e++){
      _Float16 hh = (_Float16)vv[e];
      Hv[e] = hh; Lv[e] = (_Float16)(vv[e] - (float)hh);
      const int d = c0 + j*8 + e;
      lh[d*72 + n] = Hv[e]; ll[d*72 + n] = Lv[e];
    }
    const int db = c0 + j*8;
    *(f16x8*)&Kh[kbase + (db ^ sw)] = Hv;
    *(f16x8*)&Kl[kbase + (db ^ sw)] = Lv;
  }
  __syncthreads();
  const int d = threadIdx.x>>2, n0c = (threadIdx.x&3)*16;
  const size_t vbase = ((size_t)bh*64 + d)*1024 + t*64;
  const int sw2 = (d&7)*8;
  #pragma unroll
  for (int j = 0; j < 2; j++){
    const int nb = n0c + j*8;
    *(f16x8*)&Vh[vbase + (nb ^ sw2)] = *(const f16x8*)&lh[d*72 + nb];
    *(f16x8*)&Vl[vbase + (nb ^ sw2)] = *(const f16x8*)&ll[d*72 + nb];
  }
}

// ---------------- flash attention + residual: swapped QK^T, S-pipeline (r12/r15) ----------------
// grid (32 bh, 16 qt), 256 thr, 2 blocks/CU.
__global__ __launch_bounds__(256) void k_attn(const _Float16* __restrict__ Kh, const _Float16* __restrict__ Kl,
                                              const _Float16* __restrict__ Vh, const _Float16* __restrict__ Vl,
                                              const float* __restrict__ xin, float* __restrict__ xout){
  __shared__ _Float16 smb[40960];   // 80 KB: K0,K1,K2 (8192 el each) + V0,V1 (8192 el each)
  const int tid = threadIdx.x, w = tid>>6, l = tid&63, g = l>>4, r16 = l&15;
  const int bh = blockIdx.x, qt = blockIdx.y, b = bh>>4, h = bh&15;
  const _Float16* Kbh = Kh + (size_t)bh*65536;
  const _Float16* Kbl = Kl + (size_t)bh*65536;

  size_t koffK[2], voff[2];
  int cbj[2];
  #pragma unroll
  for (int j = 0; j < 2; j++){
    const int cb = (j*4 + w)*64, c = cb + l;
    const int p  = c>>3;
    const int kp = (p&32) | ((p&12)<<1) | ((p&16)>>2) | (p&3);   // kappa(p)
    cbj[j]   = cb;
    koffK[j] = (size_t)kp*64 + (size_t)(l&7)*8;
    voff[j]  = ((size_t)bh*64 + (c>>3))*1024 + (size_t)(c&7)*8;
  }
  #define KSTAGE(PK, T) { _Pragma("unroll")                                          \
    for (int j = 0; j < 2; j++){                                                      \
      gload_lds16(Kbh + (size_t)(T)*4096 + koffK[j], (PK) + cbj[j]*8);                \
      gload_lds16(Kbl + (size_t)(T)*4096 + koffK[j], (PK) + 4096 + cbj[j]*8);         \
    } }
  #define VSTAGE(PV, T) { _Pragma("unroll")                                          \
    for (int j = 0; j < 2; j++){                                                      \
      gload_lds16(Vh + voff[j] + (T)*64, (PV) + cbj[j]*8);                            \
      gload_lds16(Vl + voff[j] + (T)*64, (PV) + 4096 + cbj[j]*8);                     \
    } }

  _Float16* pKo = smb;
  _Float16* pKn = smb + 8192;
  _Float16* pKs = smb + 16384;
  _Float16* pVc = smb + 24576;
  _Float16* pVs = smb + 32768;

  KSTAGE(pKo, 0); KSTAGE(pKn, 1); VSTAGE(pVc, 0);
  const int qrow = w*16 + r16;
  const int phq8 = PHI(qrow)*8;
  const size_t qb = (size_t)qt*4096 + (size_t)qrow*64;
  const f16x8 aqh0 = *(const f16x8*)&Kbh[qb + ((g*8) ^ phq8)];
  const f16x8 aqh1 = *(const f16x8*)&Kbh[qb + ((32 + g*8) ^ phq8)];
  const f16x8 aql0 = *(const f16x8*)&Kbl[qb + ((g*8) ^ phq8)];
  const f16x8 aql1 = *(const f16x8*)&Kbl[qb + ((32 + g*8) ^ phq8)];
  __syncthreads();

  const int swk8 = (r16&7)*8;
  float mI = -1e30f, lI = 0.f;
  f32x4 acc[4], sA[4], sB[4];
  #pragma unroll
  for (int i = 0; i < 4; i++) acc[i] = (f32x4){0.f,0.f,0.f,0.f};

  #define QKT(PK, SD) { const _Float16* kt_h = (PK); const _Float16* kt_l = (PK) + 4096;  \
    _Pragma("unroll")                                                                      \
    for (int c = 0; c < 4; c++){                                                           \
      const int rk = c*16 + r16;                                                           \
      const f16x8 kh0 = *(const f16x8*)&kt_h[rk*64 + ((g*8) ^ swk8)];                      \
      const f16x8 kh1 = *(const f16x8*)&kt_h[rk*64 + ((32+g*8) ^ swk8)];                   \
      const f16x8 kl0 = *(const f16x8*)&kt_l[rk*64 + ((g*8) ^ swk8)];                      \
      const f16x8 kl1 = *(const f16x8*)&kt_l[rk*64 + ((32+g*8) ^ swk8)];                   \
      f32x4 z = (f32x4){0.f,0.f,0.f,0.f};                                                  \
      z = mfma16h(kh0, aqh0, z);                                                           \
      z = mfma16h(kh1, aqh1, z);                                                           \
      z = mfma16h(kh0, aql0, z);                                                           \
      z = mfma16h(kh1, aql1, z);                                                           \
      z = mfma16h(kl0, aqh0, z);                                                           \
      z = mfma16h(kl1, aqh1, z);                                                           \
      (SD)[c] = z;                                                                         \
    } }

  #define SMAXPV(SC) {                                                                     \
    float rmax = (SC)[0][0];                                                               \
    _Pragma("unroll")                                                                      \
    for (int c = 0; c < 4; c++)                                                            \
      _Pragma("unroll")                                                                    \
      for (int i = 0; i < 4; i++) rmax = fmaxf(rmax, (SC)[c][i]);                          \
    rmax = fmaxf(rmax, __shfl_xor(rmax, 16));                                              \
    rmax = fmaxf(rmax, __shfl_xor(rmax, 32));                                              \
    if (__any(rmax - mI > 44.36f)){                                                        \
      const float mn = fmaxf(mI, rmax);                                                    \
      const float fac = exp2f((mI - mn)*EXPC);                                             \
      lI *= fac;                                                                           \
      mI = mn;                                                                             \
      _Pragma("unroll")                                                                    \
      for (int i = 0; i < 4; i++){                                                         \
        const float fi = __shfl(fac, g*4 + i);                                             \
        _Pragma("unroll")                                                                  \
        for (int dc = 0; dc < 4; dc++) acc[dc][i] *= fi;                                   \
      }                                                                                    \
    }                                                                                      \
    const float mC = mI*EXPC;                                                              \
    float rsum = 0.f;                                                                      \
    f16x8 aph[2], apl[2];                                                                  \
    _Pragma("unroll")                                                                      \
    for (int c = 0; c < 4; c++)                                                            \
      _Pragma("unroll")                                                                    \
      for (int i = 0; i < 4; i++){                                                         \
        const float p = exp2f(fmaf((SC)[c][i], EXPC, -mC));                                \
        const _Float16 ph = (_Float16)p;                                                   \
        aph[c>>1][(c&1)*4 + i] = ph;                                                       \
        apl[c>>1][(c&1)*4 + i] = (_Float16)(p - (float)ph);                                \
        rsum += p;                                                                         \
      }                                                                                    \
    rsum += __shfl_xor(rsum, 16);                                                          \
    rsum += __shfl_xor(rsum, 32);                                                          \
    lI += rsum;                                                                            \
    const _Float16* vt_h = pVc; const _Float16* vt_l = pVc + 4096;                         \
    _Pragma("unroll")                                                                      \
    for (int ks = 0; ks < 2; ks++){                                                        \
      _Pragma("unroll")                                                                    \
      for (int dc = 0; dc < 4; dc++){                                                      \
        const int vr = dc*16 + r16;                                                        \
        const f16x8 bvh = *(const f16x8*)&vt_h[vr*64 + ((ks*32 + g*8) ^ swk8)];            \
        const f16x8 bvl = *(const f16x8*)&vt_l[vr*64 + ((ks*32 + g*8) ^ swk8)];            \
        acc[dc] = mfma16h(aph[ks], bvh, acc[dc]);                                          \
        acc[dc] = mfma16h(apl[ks], bvh, acc[dc]);                                          \
        acc[dc] = mfma16h(aph[ks], bvl, acc[dc]);                                          \
      }                                                                                    \
    } }

  QKT(pKo, sA);

  for (int tt = 0; tt < 8; tt++){
    {
      const int t = 2*tt;
      if (t < 14) KSTAGE(pKs, t+2);
      VSTAGE(pVs, t+1);
      QKT(pKn, sB);
      SMAXPV(sA);
      __syncthreads();
      _Float16* tk = pKo; pKo = pKn; pKn = pKs; pKs = tk;
      _Float16* tv = pVc; pVc = pVs; pVs = tv;
    }
    {
      const int t = 2*tt+1;
      if (t < 14) KSTAGE(pKs, t+2);
      if (t < 15) VSTAGE(pVs, t+1);
      if (t < 15) QKT(pKn, sA);
      SMAXPV(sB);
      __syncthreads();
      _Float16* tk = pKo; pKo = pKn; pKn = pKs; pKs = tk;
      _Float16* tv = pVc; pVc = pVs; pVs = tv;
    }
  }
  #undef KSTAGE
  #undef VSTAGE
  #undef QKT
  #undef SMAXPV

  #pragma unroll
  for (int i = 0; i < 4; i++){
    const float li = __shfl(lI, g*4 + i);
    const float inv = 1.f/li;
    const int row = qt*64 + w*16 + g*4 + i;
    #pragma unroll
    for (int dc = 0; dc < 4; dc++){
      const size_t idx = (size_t)b*1048576 + (size_t)row*1024 + h*64 + dc*16 + r16;
      xout[idx] = acc[dc][i]*inv + xin[idx];
    }
  }
}

// ---------------- layernorm; SPLIT=1 writes fp16 hi/lo in swizzled A-layout ----------------
template<int SPLIT>
__global__ __launch_bounds__(256) void k_ln(const float* __restrict__ x, const float* __restrict__ gg,
                                            const float* __restrict__ bb, float* __restrict__ outf,
                                            _Float16* __restrict__ Oh, _Float16* __restrict__ Ol){
  const int row = blockIdx.x*4 + (threadIdx.x>>6);
  const int lane = threadIdx.x & 63;
  const float* xr = x + (size_t)row*1024;
  f32x4 v[4];
  float s = 0.f, q = 0.f;
  #pragma unroll
  for (int c = 0; c < 2; c++){
    v[c*2]   = *(const f32x4*)(xr + c*512 + lane*8);
    v[c*2+1] = *(const f32x4*)(xr + c*512 + lane*8 + 4);
    #pragma unroll
    for (int e = 0; e < 4; e++){
      s += v[c*2][e] + v[c*2+1][e];
      q += v[c*2][e]*v[c*2][e] + v[c*2+1][e]*v[c*2+1][e];
    }
  }
  for (int d = 1; d < 64; d <<= 1){ s += __shfl_xor(s,d); q += __shfl_xor(q,d); }
  const float mean = s * (1.f/1024.f);
  const float var  = q * (1.f/1024.f) - mean*mean;
  const float rstd = rsqrtf(var + 1e-5f);
  #pragma unroll
  for (int c = 0; c < 2; c++){
    const int col = c*512 + lane*8;
    f32x4 g0 = *(const f32x4*)(gg + col), g1 = *(const f32x4*)(gg + col + 4);
    f32x4 b0 = *(const f32x4*)(bb + col), b1 = *(const f32x4*)(bb + col + 4);
    float h[8];
    #pragma unroll
    for (int e = 0; e < 4; e++){
      h[e]   = (v[c*2][e]  -mean)*rstd*g0[e] + b0[e];
      h[e+4] = (v[c*2+1][e]-mean)*rstd*g1[e] + b1[e];
    }
    if (SPLIT){
      f16x8 Hv, Lv;
      #pragma unroll
      for (int e = 0; e < 8; e++){
        _Float16 hh = (_Float16)h[e];
        Hv[e] = hh; Lv[e] = (_Float16)(h[e] - (float)hh);
      }
      const size_t addr = (size_t)row*1024 + c*512 + (lane>>3)*64 + (((lane&7)*8) ^ ((row&7)*8));
      *(f16x8*)&Oh[addr] = Hv;
      *(f16x8*)&Ol[addr] = Lv;
    } else {
      f32x4 o0, o1;
      #pragma unroll
      for (int e = 0; e < 4; e++){ o0[e] = h[e]; o1[e] = h[e+4]; }
      *(f32x4*)(outf + (size_t)row*1024 + col) = o0;
      *(f32x4*)(outf + (size_t)row*1024 + col + 4) = o1;
    }
  }
}

// ---------------- bitlinear GEMM: C[2048,1024] = (Ah+Al).Wb^T * beta ----------------
// BM=32, BN=64, BK=64, grid (16,64) = 1024 blocks = 4 blocks/CU (16 waves/CU) for
// latency hiding across the per-K-tile barrier drains. 4 waves (2Mx2N), wave-tile
// 16x32, dbuf 32KB. (r15 version — best measured; r16's counted-vmcnt regressed.)
// MODE 0: GELU -> split fp16 out (swizzled A-layout).
// MODE 1: += into fp32 residual; if Kh!=null, ALSO produce next layer's K/V splits
//         (block == half of a presplit unit: tseq=by>>1&15, half=by&1, head=bx).
template<int MODE>
__global__ __launch_bounds__(256) void k_gemm(const _Float16* __restrict__ Ah, const _Float16* __restrict__ Al,
                                              const _Float16* __restrict__ Wg,
                                              float* __restrict__ out32,
                                              _Float16* __restrict__ Oh, _Float16* __restrict__ Ol,
                                              const double* __restrict__ dabs_slot,
                                              _Float16* __restrict__ Kh, _Float16* __restrict__ Kl,
                                              _Float16* __restrict__ Vh, _Float16* __restrict__ Vl){
  __shared__ _Float16 smb[16384];   // 32KB: 2 x (A-hi 2048 + A-lo 2048 + B 4096); reused post-loop
  const int tid = threadIdx.x, w = tid>>6, l = tid&63, g = l>>4, r16 = l&15;
  const int wm = w>>1, wn = w&1;
  const int n0 = blockIdx.x*64, m0 = blockIdx.y*32;
  const float scale = (float)(*dabs_slot * (1.0/1048576.0));
  const int swr = (r16&7)*8;
  f32x4 acc[2] = {};
  // staging: A-hi 4KB (wave w -> rows w*8..+7), A-lo 4KB, B 8KB (chunks j*4+w)
  #define STAGE(buf, k0) { _Float16* Bp = smb + (buf)*8192;                               \
    gload_lds16(Ah + (size_t)(m0 + w*8 + (l>>3))*1024 + (k0) + (l&7)*8, Bp + w*512);      \
    gload_lds16(Al + (size_t)(m0 + w*8 + (l>>3))*1024 + (k0) + (l&7)*8, Bp + 2048 + w*512);\
    _Pragma("unroll")                                                                     \
    for (int j = 0; j < 2; j++){                                                          \
      const int ch = j*4 + w;                                                             \
      gload_lds16(Wg + (size_t)(n0 + ch*8 + (l>>3))*1024 + (k0) + (l&7)*8,                \
                  Bp + 4096 + ch*512);                                                    \
    } }
  STAGE(0, 0);
  __syncthreads();
  for (int t = 0; t < 16; t++){
    if (t < 15) STAGE((t+1)&1, (t+1)*64);
    const _Float16* Bp = smb + (t&1)*8192;
    #pragma unroll
    for (int kk = 0; kk < 2; kk++){
      const int col = (kk*32 + g*8) ^ swr;
      const int arow = wm*16 + r16;
      const f16x8 ah = *(const f16x8*)&Bp[arow*64 + col];
      const f16x8 al = *(const f16x8*)&Bp[2048 + arow*64 + col];
      const f16x8 bf0 = *(const f16x8*)&Bp[4096 + (wn*32 + r16)*64 + col];
      const f16x8 bf1 = *(const f16x8*)&Bp[4096 + (wn*32 + 16 + r16)*64 + col];
      acc[0] = mfma16h(ah, bf0, acc[0]);
      acc[0] = mfma16h(al, bf0, acc[0]);
      acc[1] = mfma16h(ah, bf1, acc[1]);
      acc[1] = mfma16h(al, bf1, acc[1]);
    }
    __syncthreads();
  }
  #undef STAGE
  // post-loop LDS reuse (all waves past final barrier): split-tile staging for fused KV
  _Float16* kh_t = smb;            // [32][72] token-major hi
  _Float16* kl_t = smb + 2304;     // [32][72] token-major lo
  _Float16* lhv  = smb + 4608;     // [64][40] d-major hi (32 token cols)
  _Float16* llv  = smb + 7168;     // [64][40] d-major lo
  #pragma unroll
  for (int ni = 0; ni < 2; ni++)
    #pragma unroll
    for (int i = 0; i < 4; i++){
      const int rr = m0 + wm*16 + g*4 + i;
      const int cc = n0 + wn*32 + ni*16 + r16;
      float vv = acc[ni][i] * scale;
      if (MODE == 0){
        vv = 0.5f*vv*(1.f + erff(vv*0.70710678118f));
        _Float16 hh = (_Float16)vv;
        const size_t addr = (size_t)rr*1024 + (cc & ~63) + ((cc & 63) ^ ((rr&7)*8));
        Oh[addr] = hh;
        Ol[addr] = (_Float16)(vv - (float)hh);
      } else {
        const size_t idx = (size_t)rr*1024 + cc;
        const float xnew = out32[idx] + vv;
        out32[idx] = xnew;
        if (Kh){
          const int nl = wm*16 + g*4 + i;          // token within 32-tile
          const int dl = wn*32 + ni*16 + r16;      // d within head
          const _Float16 hh = (_Float16)xnew;
          const _Float16 lo = (_Float16)(xnew - (float)hh);
          kh_t[nl*72 + dl] = hh;  kl_t[nl*72 + dl] = lo;
          lhv [dl*40 + nl] = hh;  llv [dl*40 + nl] = lo;
        }
      }
    }
  if (MODE == 1 && Kh){
    __syncthreads();
    const int bh2  = (blockIdx.y>>5)*16 + blockIdx.x;   // batch*16 + head
    const int tseq = (blockIdx.y>>1) & 15;              // 64-token KV tile
    const int half = blockIdx.y & 1;                    // which 32-token half
    // K: 32 rows x 64 d, one f16x8 per thread per buffer
    const int n = tid>>3, c0q = (tid&7)*8;
    const size_t kbase = ((size_t)bh2*1024 + tseq*64 + half*32 + n)*64;
    const int swn = PHI(n)*8;    // PHI reads bits 3,1,0 only -> half-offset transparent
    *(f16x8*)&Kh[kbase + (c0q ^ swn)] = *(const f16x8*)&kh_t[n*72 + c0q];
    *(f16x8*)&Kl[kbase + (c0q ^ swn)] = *(const f16x8*)&kl_t[n*72 + c0q];
    // V: 64 d x 32 token-cols, one f16x8 per thread per buffer
    const int d = tid>>2, lb = (tid&3)*8;
    const size_t vbase = ((size_t)bh2*64 + d)*1024 + tseq*64;
    const int sw2 = (d&7)*8;
    const int colw = (half*32 + lb) ^ sw2;   // 8-aligned (sw2 only touches bits 3..5)
    *(f16x8*)&Vh[vbase + colw] = *(const f16x8*)&lhv[d*40 + lb];
    *(f16x8*)&Vl[vbase + colw] = *(const f16x8*)&llv[d*40 + lb];
  }
}

extern "C" void kernel_launch(void* const* d_in, const int* in_sizes, int n_in,
                              void* d_out, int out_size, void* d_ws, size_t ws_size,
                              hipStream_t stream){
  const float* x_in = (const float*)d_in[0];
  const float* ln_g = (const float*)d_in[1];
  const float* ln_b = (const float*)d_in[2];
  const float* w1   = (const float*)d_in[3];
  const float* w2   = (const float*)d_in[4];
  const float* fg   = (const float*)d_in[5];
  const float* fb   = (const float*)d_in[6];

  char* ws = (char*)d_ws;
  double*   dsum  = (double*)ws;            // 12
  double*   dabs  = (double*)(ws + 96);     // 12
  _Float16* wb = (_Float16*)(ws + 256);     // 12 * 1M fp16 = 24 MB
  size_t o = 256 + 12ull*1048576ull*2ull;
  float* xA = (float*)(ws + o); o += 2048ull*1024*4;
  float* xB = (float*)(ws + o); o += 2048ull*1024*4;
  _Float16* Kh = (_Float16*)(ws + o); o += 2048ull*1024*2;
  _Float16* Kl = (_Float16*)(ws + o); o += 2048ull*1024*2;
  _Float16* Vh = (_Float16*)(ws + o); o += 2048ull*1024*2;
  _Float16* Vl = (_Float16*)(ws + o); o += 2048ull*1024*2;
  _Float16* Ahb = (_Float16*)(ws + o); o += 2048ull*1024*2;
  _Float16* Alb = (_Float16*)(ws + o); o += 2048ull*1024*2;
  _Float16* Ghb = (_Float16*)(ws + o); o += 2048ull*1024*2;
  _Float16* Glb = (_Float16*)(ws + o); o += 2048ull*1024*2;

  hipMemsetAsync(ws, 0, 256, stream);
  k_wstats  <<<dim3(32,12), 256, 0, stream>>>(w1, w2, dsum, dabs);
  k_binarize<<<6144,        256, 0, stream>>>(w1, w2, dsum, wb);
  k_presplit<<<dim3(16,32), 256, 0, stream>>>(x_in, Kh, Kl, Vh, Vl);

  const float* xc = x_in;
  for (int i = 0; i < 6; i++){
    float* xn = (i & 1) ? xB : xA;
    const bool last = (i == 5);
    k_attn    <<<dim3(32,16), 256, 0, stream>>>(Kh, Kl, Vh, Vl, xc, xn);
    k_ln<1>   <<<512, 256, 0, stream>>>(xn, ln_g + (size_t)i*1024, ln_b + (size_t)i*1024,
                                        nullptr, Ahb, Alb);
    k_gemm<0> <<<dim3(16,64), 256, 0, stream>>>(Ahb, Alb, wb + (size_t)i*1048576,
                                                nullptr, Ghb, Glb, &dabs[i],
                                                nullptr, nullptr, nullptr, nullptr);
    k_gemm<1> <<<dim3(16,64), 256, 0, stream>>>(Ghb, Glb, wb + (size_t)(6+i)*1048576,
                                                xn, nullptr, nullptr, &dabs[6+i],
                                                last ? nullptr : Kh, last ? nullptr : Kl,
                                                last ? nullptr : Vh, last ? nullptr : Vl);
    xc = xn;
  }
  k_ln<0><<<512, 256, 0, stream>>>(xc, fg, fb, (float*)d_out, nullptr, nullptr);
}

// Round 18
// 478.747 us; speedup vs baseline: 1.0937x; 1.0528x over previous
//
#include <hip/hip_runtime.h>
#include <math.h>

typedef __attribute__((ext_vector_type(4))) float f32x4;
typedef __attribute__((ext_vector_type(8))) _Float16 f16x8;

__device__ __forceinline__ f32x4 mfma16h(f16x8 a, f16x8 b, f32x4 c){
  return __builtin_amdgcn_mfma_f32_16x16x32_f16(a, b, c, 0, 0, 0);
}
__device__ __forceinline__ void gload_lds16(const void* g, void* l){
  __builtin_amdgcn_global_load_lds((const __attribute__((address_space(1))) void*)g,
                                   (__attribute__((address_space(3))) void*)l, 16, 0, 0);
}

#define EXPC 0.1803368801111204f   // 0.125 * log2(e)
// global K swizzle phi(n) = bits (n3,n1,n0): chosen so phi(kappa(p)) = p&7 ->
// attn K-read XOR is (r16&7)*8, sequential across lanes = conflict-free (r10-verified).
#define PHI(n) (((((n)>>3)&1)<<2) | ((((n)>>1)&1)<<1) | ((n)&1))

// ---------------- weight stats: alpha=mean(w), beta-sum=sum|w| ----------------
__global__ __launch_bounds__(256) void k_wstats(const float* __restrict__ w1, const float* __restrict__ w2,
                                                double* __restrict__ dsum, double* __restrict__ dabs){
  const int mat = blockIdx.y;
  const float* wp = (mat < 6) ? (w1 + (size_t)mat*1048576) : (w2 + (size_t)(mat-6)*1048576);
  const f32x4* wv = (const f32x4*)wp + (size_t)blockIdx.x*8192;
  double s = 0.0, a = 0.0;
  for (int j = 0; j < 32; j++){
    f32x4 v = wv[j*256 + threadIdx.x];
    s += (double)v.x + (double)v.y + (double)v.z + (double)v.w;
    a += (double)fabsf(v.x) + (double)fabsf(v.y) + (double)fabsf(v.z) + (double)fabsf(v.w);
  }
  for (int d = 1; d < 64; d <<= 1){ s += __shfl_xor(s, d); a += __shfl_xor(a, d); }
  __shared__ double red[8];
  const int w = threadIdx.x >> 6;
  if ((threadIdx.x & 63) == 0){ red[w*2] = s; red[w*2+1] = a; }
  __syncthreads();
  if (threadIdx.x == 0){
    double S = red[0]+red[2]+red[4]+red[6], A = red[1]+red[3]+red[5]+red[7];
    atomicAdd(&dsum[mat], S);
    atomicAdd(&dabs[mat], A);
  }
}

// ---------------- binarize weights to fp16 {-1,0,+1}, swizzled GEMM-B layout ----------------
// layout: wb[mat][n][ (k&~63) + ((k&63) ^ 8*(n&7)) ]
__global__ __launch_bounds__(256) void k_binarize(const float* __restrict__ w1, const float* __restrict__ w2,
                                                  const double* __restrict__ dsum, _Float16* __restrict__ wb){
  const int blk = blockIdx.x;          // 6144 blocks, 512 per matrix
  const int mat = blk >> 9;
  const float alpha = (float)(dsum[mat] * (1.0/1048576.0));
  const float* wp = (mat < 6) ? (w1 + (size_t)mat*1048576) : (w2 + (size_t)(mat-6)*1048576);
  const size_t off = (size_t)(blk & 511)*2048 + (size_t)threadIdx.x*8;
  const int n = (int)(off >> 10), k = (int)(off & 1023);
  f32x4 v0 = *(const f32x4*)(wp + off), v1 = *(const f32x4*)(wp + off + 4);
  float vv[8] = {v0.x,v0.y,v0.z,v0.w,v1.x,v1.y,v1.z,v1.w};
  f16x8 pk;
  #pragma unroll
  for (int e = 0; e < 8; e++){
    float d = vv[e] - alpha;
    pk[e] = d > 0.f ? (_Float16)1.0f : (d < 0.f ? (_Float16)(-1.0f) : (_Float16)0.0f);
  }
  const size_t addr = (size_t)mat*1048576 + (size_t)n*1024 + (size_t)((k & ~63) + ((k & 63) ^ ((n&7)*8)));
  *(f16x8*)&wb[addr] = pk;
}

// ---------------- presplit (layer 0 only): x -> fp16 hi/lo K-layout + V^T-layout ----------------
// K:  Kh/Kl[bh][n][ d ^ 8*PHI(n&63) ]
// VT: Vh/Vl[bh][d][ t*64 + ((n&63) ^ 8*(d&7)) ]
__global__ __launch_bounds__(256) void k_presplit(const float* __restrict__ x,
                                                  _Float16* __restrict__ Kh, _Float16* __restrict__ Kl,
                                                  _Float16* __restrict__ Vh, _Float16* __restrict__ Vl){
  __shared__ _Float16 lh[64*72], ll[64*72];
  const int t = blockIdx.x, bh = blockIdx.y, b = bh>>4, h = bh&15;
  const int n = threadIdx.x>>2, c0 = (threadIdx.x&3)*16;
  const float* src = x + (size_t)b*1048576 + (size_t)(t*64+n)*1024 + h*64 + c0;
  const size_t kbase = ((size_t)bh*1024 + t*64 + n)*64;
  const int sw = PHI(n)*8;
  #pragma unroll
  for (int j = 0; j < 2; j++){
    f32x4 v0 = *(const f32x4*)(src + j*8);
    f32x4 v1 = *(const f32x4*)(src + j*8 + 4);
    float vv[8] = {v0.x,v0.y,v0.z,v0.w,v1.x,v1.y,v1.z,v1.w};
    f16x8 Hv, Lv;
    #pragma unroll
    for (int e = 0; e < 8; e++){
      _Float16 hh = (_Float16)vv[e];
      Hv[e] = hh; Lv[e] = (_Float16)(vv[e] - (float)hh);
      const int d = c0 + j*8 + e;
      lh[d*72 + n] = Hv[e]; ll[d*72 + n] = Lv[e];
    }
    const int db = c0 + j*8;
    *(f16x8*)&Kh[kbase + (db ^ sw)] = Hv;
    *(f16x8*)&Kl[kbase + (db ^ sw)] = Lv;
  }
  __syncthreads();
  const int d = threadIdx.x>>2, n0c = (threadIdx.x&3)*16;
  const size_t vbase = ((size_t)bh*64 + d)*1024 + t*64;
  const int sw2 = (d&7)*8;
  #pragma unroll
  for (int j = 0; j < 2; j++){
    const int nb = n0c + j*8;
    *(f16x8*)&Vh[vbase + (nb ^ sw2)] = *(const f16x8*)&lh[d*72 + nb];
    *(f16x8*)&Vl[vbase + (nb ^ sw2)] = *(const f16x8*)&ll[d*72 + nb];
  }
}

// ---------------- flash attention + residual: swapped QK^T, S-pipeline (r12/r15) ----------------
// grid (32 bh, 16 qt), 256 thr, 2 blocks/CU. (flat%8 = bh%8 -> already XCD-local.)
__global__ __launch_bounds__(256) void k_attn(const _Float16* __restrict__ Kh, const _Float16* __restrict__ Kl,
                                              const _Float16* __restrict__ Vh, const _Float16* __restrict__ Vl,
                                              const float* __restrict__ xin, float* __restrict__ xout){
  __shared__ _Float16 smb[40960];   // 80 KB: K0,K1,K2 (8192 el each) + V0,V1 (8192 el each)
  const int tid = threadIdx.x, w = tid>>6, l = tid&63, g = l>>4, r16 = l&15;
  const int bh = blockIdx.x, qt = blockIdx.y, b = bh>>4, h = bh&15;
  const _Float16* Kbh = Kh + (size_t)bh*65536;
  const _Float16* Kbl = Kl + (size_t)bh*65536;

  size_t koffK[2], voff[2];
  int cbj[2];
  #pragma unroll
  for (int j = 0; j < 2; j++){
    const int cb = (j*4 + w)*64, c = cb + l;
    const int p  = c>>3;
    const int kp = (p&32) | ((p&12)<<1) | ((p&16)>>2) | (p&3);   // kappa(p)
    cbj[j]   = cb;
    koffK[j] = (size_t)kp*64 + (size_t)(l&7)*8;
    voff[j]  = ((size_t)bh*64 + (c>>3))*1024 + (size_t)(c&7)*8;
  }
  #define KSTAGE(PK, T) { _Pragma("unroll")                                          \
    for (int j = 0; j < 2; j++){                                                      \
      gload_lds16(Kbh + (size_t)(T)*4096 + koffK[j], (PK) + cbj[j]*8);                \
      gload_lds16(Kbl + (size_t)(T)*4096 + koffK[j], (PK) + 4096 + cbj[j]*8);         \
    } }
  #define VSTAGE(PV, T) { _Pragma("unroll")                                          \
    for (int j = 0; j < 2; j++){                                                      \
      gload_lds16(Vh + voff[j] + (T)*64, (PV) + cbj[j]*8);                            \
      gload_lds16(Vl + voff[j] + (T)*64, (PV) + 4096 + cbj[j]*8);                     \
    } }

  _Float16* pKo = smb;
  _Float16* pKn = smb + 8192;
  _Float16* pKs = smb + 16384;
  _Float16* pVc = smb + 24576;
  _Float16* pVs = smb + 32768;

  KSTAGE(pKo, 0); KSTAGE(pKn, 1); VSTAGE(pVc, 0);
  const int qrow = w*16 + r16;
  const int phq8 = PHI(qrow)*8;
  const size_t qb = (size_t)qt*4096 + (size_t)qrow*64;
  const f16x8 aqh0 = *(const f16x8*)&Kbh[qb + ((g*8) ^ phq8)];
  const f16x8 aqh1 = *(const f16x8*)&Kbh[qb + ((32 + g*8) ^ phq8)];
  const f16x8 aql0 = *(const f16x8*)&Kbl[qb + ((g*8) ^ phq8)];
  const f16x8 aql1 = *(const f16x8*)&Kbl[qb + ((32 + g*8) ^ phq8)];
  __syncthreads();

  const int swk8 = (r16&7)*8;
  float mI = -1e30f, lI = 0.f;
  f32x4 acc[4], sA[4], sB[4];
  #pragma unroll
  for (int i = 0; i < 4; i++) acc[i] = (f32x4){0.f,0.f,0.f,0.f};

  #define QKT(PK, SD) { const _Float16* kt_h = (PK); const _Float16* kt_l = (PK) + 4096;  \
    _Pragma("unroll")                                                                      \
    for (int c = 0; c < 4; c++){                                                           \
      const int rk = c*16 + r16;                                                           \
      const f16x8 kh0 = *(const f16x8*)&kt_h[rk*64 + ((g*8) ^ swk8)];                      \
      const f16x8 kh1 = *(const f16x8*)&kt_h[rk*64 + ((32+g*8) ^ swk8)];                   \
      const f16x8 kl0 = *(const f16x8*)&kt_l[rk*64 + ((g*8) ^ swk8)];                      \
      const f16x8 kl1 = *(const f16x8*)&kt_l[rk*64 + ((32+g*8) ^ swk8)];                   \
      f32x4 z = (f32x4){0.f,0.f,0.f,0.f};                                                  \
      z = mfma16h(kh0, aqh0, z);                                                           \
      z = mfma16h(kh1, aqh1, z);                                                           \
      z = mfma16h(kh0, aql0, z);                                                           \
      z = mfma16h(kh1, aql1, z);                                                           \
      z = mfma16h(kl0, aqh0, z);                                                           \
      z = mfma16h(kl1, aqh1, z);                                                           \
      (SD)[c] = z;                                                                         \
    } }

  #define SMAXPV(SC) {                                                                     \
    float rmax = (SC)[0][0];                                                               \
    _Pragma("unroll")                                                                      \
    for (int c = 0; c < 4; c++)                                                            \
      _Pragma("unroll")                                                                    \
      for (int i = 0; i < 4; i++) rmax = fmaxf(rmax, (SC)[c][i]);                          \
    rmax = fmaxf(rmax, __shfl_xor(rmax, 16));                                              \
    rmax = fmaxf(rmax, __shfl_xor(rmax, 32));                                              \
    if (__any(rmax - mI > 44.36f)){                                                        \
      const float mn = fmaxf(mI, rmax);                                                    \
      const float fac = exp2f((mI - mn)*EXPC);                                             \
      lI *= fac;                                                                           \
      mI = mn;                                                                             \
      _Pragma("unroll")                                                                    \
      for (int i = 0; i < 4; i++){                                                         \
        const float fi = __shfl(fac, g*4 + i);                                             \
        _Pragma("unroll")                                                                  \
        for (int dc = 0; dc < 4; dc++) acc[dc][i] *= fi;                                   \
      }                                                                                    \
    }                                                                                      \
    const float mC = mI*EXPC;                                                              \
    float rsum = 0.f;                                                                      \
    f16x8 aph[2], apl[2];                                                                  \
    _Pragma("unroll")                                                                      \
    for (int c = 0; c < 4; c++)                                                            \
      _Pragma("unroll")                                                                    \
      for (int i = 0; i < 4; i++){                                                         \
        const float p = exp2f(fmaf((SC)[c][i], EXPC, -mC));                                \
        const _Float16 ph = (_Float16)p;                                                   \
        aph[c>>1][(c&1)*4 + i] = ph;                                                       \
        apl[c>>1][(c&1)*4 + i] = (_Float16)(p - (float)ph);                                \
        rsum += p;                                                                         \
      }                                                                                    \
    rsum += __shfl_xor(rsum, 16);                                                          \
    rsum += __shfl_xor(rsum, 32);                                                          \
    lI += rsum;                                                                            \
    const _Float16* vt_h = pVc; const _Float16* vt_l = pVc + 4096;                         \
    _Pragma("unroll")                                                                      \
    for (int ks = 0; ks < 2; ks++){                                                        \
      _Pragma("unroll")                                                                    \
      for (int dc = 0; dc < 4; dc++){                                                      \
        const int vr = dc*16 + r16;                                                        \
        const f16x8 bvh = *(const f16x8*)&vt_h[vr*64 + ((ks*32 + g*8) ^ swk8)];            \
        const f16x8 bvl = *(const f16x8*)&vt_l[vr*64 + ((ks*32 + g*8) ^ swk8)];            \
        acc[dc] = mfma16h(aph[ks], bvh, acc[dc]);                                          \
        acc[dc] = mfma16h(apl[ks], bvh, acc[dc]);                                          \
        acc[dc] = mfma16h(aph[ks], bvl, acc[dc]);                                          \
      }                                                                                    \
    } }

  QKT(pKo, sA);

  for (int tt = 0; tt < 8; tt++){
    {
      const int t = 2*tt;
      if (t < 14) KSTAGE(pKs, t+2);
      VSTAGE(pVs, t+1);
      QKT(pKn, sB);
      SMAXPV(sA);
      __syncthreads();
      _Float16* tk = pKo; pKo = pKn; pKn = pKs; pKs = tk;
      _Float16* tv = pVc; pVc = pVs; pVs = tv;
    }
    {
      const int t = 2*tt+1;
      if (t < 14) KSTAGE(pKs, t+2);
      if (t < 15) VSTAGE(pVs, t+1);
      if (t < 15) QKT(pKn, sA);
      SMAXPV(sB);
      __syncthreads();
      _Float16* tk = pKo; pKo = pKn; pKn = pKs; pKs = tk;
      _Float16* tv = pVc; pVc = pVs; pVs = tv;
    }
  }
  #undef KSTAGE
  #undef VSTAGE
  #undef QKT
  #undef SMAXPV

  #pragma unroll
  for (int i = 0; i < 4; i++){
    const float li = __shfl(lI, g*4 + i);
    const float inv = 1.f/li;
    const int row = qt*64 + w*16 + g*4 + i;
    #pragma unroll
    for (int dc = 0; dc < 4; dc++){
      const size_t idx = (size_t)b*1048576 + (size_t)row*1024 + h*64 + dc*16 + r16;
      xout[idx] = acc[dc][i]*inv + xin[idx];
    }
  }
}

// ---------------- layernorm; SPLIT=1 writes fp16 hi/lo in swizzled A-layout ----------------
template<int SPLIT>
__global__ __launch_bounds__(256) void k_ln(const float* __restrict__ x, const float* __restrict__ gg,
                                            const float* __restrict__ bb, float* __restrict__ outf,
                                            _Float16* __restrict__ Oh, _Float16* __restrict__ Ol){
  const int row = blockIdx.x*4 + (threadIdx.x>>6);
  const int lane = threadIdx.x & 63;
  const float* xr = x + (size_t)row*1024;
  f32x4 v[4];
  float s = 0.f, q = 0.f;
  #pragma unroll
  for (int c = 0; c < 2; c++){
    v[c*2]   = *(const f32x4*)(xr + c*512 + lane*8);
    v[c*2+1] = *(const f32x4*)(xr + c*512 + lane*8 + 4);
    #pragma unroll
    for (int e = 0; e < 4; e++){
      s += v[c*2][e] + v[c*2+1][e];
      q += v[c*2][e]*v[c*2][e] + v[c*2+1][e]*v[c*2+1][e];
    }
  }
  for (int d = 1; d < 64; d <<= 1){ s += __shfl_xor(s,d); q += __shfl_xor(q,d); }
  const float mean = s * (1.f/1024.f);
  const float var  = q * (1.f/1024.f) - mean*mean;
  const float rstd = rsqrtf(var + 1e-5f);
  #pragma unroll
  for (int c = 0; c < 2; c++){
    const int col = c*512 + lane*8;
    f32x4 g0 = *(const f32x4*)(gg + col), g1 = *(const f32x4*)(gg + col + 4);
    f32x4 b0 = *(const f32x4*)(bb + col), b1 = *(const f32x4*)(bb + col + 4);
    float h[8];
    #pragma unroll
    for (int e = 0; e < 4; e++){
      h[e]   = (v[c*2][e]  -mean)*rstd*g0[e] + b0[e];
      h[e+4] = (v[c*2+1][e]-mean)*rstd*g1[e] + b1[e];
    }
    if (SPLIT){
      f16x8 Hv, Lv;
      #pragma unroll
      for (int e = 0; e < 8; e++){
        _Float16 hh = (_Float16)h[e];
        Hv[e] = hh; Lv[e] = (_Float16)(h[e] - (float)hh);
      }
      const size_t addr = (size_t)row*1024 + c*512 + (lane>>3)*64 + (((lane&7)*8) ^ ((row&7)*8));
      *(f16x8*)&Oh[addr] = Hv;
      *(f16x8*)&Ol[addr] = Lv;
    } else {
      f32x4 o0, o1;
      #pragma unroll
      for (int e = 0; e < 4; e++){ o0[e] = h[e]; o1[e] = h[e+4]; }
      *(f32x4*)(outf + (size_t)row*1024 + col) = o0;
      *(f32x4*)(outf + (size_t)row*1024 + col + 4) = o1;
    }
  }
}

// ---------------- bitlinear GEMM: C[2048,1024] = (Ah+Al).Wb^T * beta ----------------
// BM=32, BN=64, BK=64, grid (16,64) = 1024 blocks = 4 blocks/CU. r15 schedule (best).
// T1 XCD swizzle: flat launch id -> nf = (flat&7)*128 + (flat>>3), so each XCD owns a
// contiguous 8-row-tile band: per-XCD L2 footprint = 1MB A-slice + 2MB W = 3MB <= 4MB
// (default x-major round-robin made every XCD touch all 8MB of A -> L2 thrash to L3).
// Bijective (1024 = 8*128) -> output bit-identical.
// MODE 0: GELU -> split fp16 out (swizzled A-layout).
// MODE 1: += into fp32 residual; if Kh!=null, ALSO produce next layer's K/V splits
//         (block == half of a presplit unit: tseq=by2>>1&15, half=by2&1, head=bx2).
template<int MODE>
__global__ __launch_bounds__(256) void k_gemm(const _Float16* __restrict__ Ah, const _Float16* __restrict__ Al,
                                              const _Float16* __restrict__ Wg,
                                              float* __restrict__ out32,
                                              _Float16* __restrict__ Oh, _Float16* __restrict__ Ol,
                                              const double* __restrict__ dabs_slot,
                                              _Float16* __restrict__ Kh, _Float16* __restrict__ Kl,
                                              _Float16* __restrict__ Vh, _Float16* __restrict__ Vl){
  __shared__ _Float16 smb[16384];   // 32KB: 2 x (A-hi 2048 + A-lo 2048 + B 4096); reused post-loop
  const int tid = threadIdx.x, w = tid>>6, l = tid&63, g = l>>4, r16 = l&15;
  const int wm = w>>1, wn = w&1;
  const int flat = blockIdx.y*16 + blockIdx.x;        // launch-order id (x-major)
  const int nf   = (flat & 7)*128 + (flat >> 3);      // XCD-contiguous remap (bijective)
  const int bx2  = nf & 15, by2 = nf >> 4;
  const int n0 = bx2*64, m0 = by2*32;
  const float scale = (float)(*dabs_slot * (1.0/1048576.0));
  const int swr = (r16&7)*8;
  f32x4 acc[2] = {};
  // staging: A-hi 4KB (wave w -> rows w*8..+7), A-lo 4KB, B 8KB (chunks j*4+w)
  #define STAGE(buf, k0) { _Float16* Bp = smb + (buf)*8192;                               \
    gload_lds16(Ah + (size_t)(m0 + w*8 + (l>>3))*1024 + (k0) + (l&7)*8, Bp + w*512);      \
    gload_lds16(Al + (size_t)(m0 + w*8 + (l>>3))*1024 + (k0) + (l&7)*8, Bp + 2048 + w*512);\
    _Pragma("unroll")                                                                     \
    for (int j = 0; j < 2; j++){                                                          \
      const int ch = j*4 + w;                                                             \
      gload_lds16(Wg + (size_t)(n0 + ch*8 + (l>>3))*1024 + (k0) + (l&7)*8,                \
                  Bp + 4096 + ch*512);                                                    \
    } }
  STAGE(0, 0);
  __syncthreads();
  for (int t = 0; t < 16; t++){
    if (t < 15) STAGE((t+1)&1, (t+1)*64);
    const _Float16* Bp = smb + (t&1)*8192;
    #pragma unroll
    for (int kk = 0; kk < 2; kk++){
      const int col = (kk*32 + g*8) ^ swr;
      const int arow = wm*16 + r16;
      const f16x8 ah = *(const f16x8*)&Bp[arow*64 + col];
      const f16x8 al = *(const f16x8*)&Bp[2048 + arow*64 + col];
      const f16x8 bf0 = *(const f16x8*)&Bp[4096 + (wn*32 + r16)*64 + col];
      const f16x8 bf1 = *(const f16x8*)&Bp[4096 + (wn*32 + 16 + r16)*64 + col];
      acc[0] = mfma16h(ah, bf0, acc[0]);
      acc[0] = mfma16h(al, bf0, acc[0]);
      acc[1] = mfma16h(ah, bf1, acc[1]);
      acc[1] = mfma16h(al, bf1, acc[1]);
    }
    __syncthreads();
  }
  #undef STAGE
  // post-loop LDS reuse (all waves past final barrier): split-tile staging for fused KV
  _Float16* kh_t = smb;            // [32][72] token-major hi
  _Float16* kl_t = smb + 2304;     // [32][72] token-major lo
  _Float16* lhv  = smb + 4608;     // [64][40] d-major hi (32 token cols)
  _Float16* llv  = smb + 7168;     // [64][40] d-major lo
  #pragma unroll
  for (int ni = 0; ni < 2; ni++)
    #pragma unroll
    for (int i = 0; i < 4; i++){
      const int rr = m0 + wm*16 + g*4 + i;
      const int cc = n0 + wn*32 + ni*16 + r16;
      float vv = acc[ni][i] * scale;
      if (MODE == 0){
        vv = 0.5f*vv*(1.f + erff(vv*0.70710678118f));
        _Float16 hh = (_Float16)vv;
        const size_t addr = (size_t)rr*1024 + (cc & ~63) + ((cc & 63) ^ ((rr&7)*8));
        Oh[addr] = hh;
        Ol[addr] = (_Float16)(vv - (float)hh);
      } else {
        const size_t idx = (size_t)rr*1024 + cc;
        const float xnew = out32[idx] + vv;
        out32[idx] = xnew;
        if (Kh){
          const int nl = wm*16 + g*4 + i;          // token within 32-tile
          const int dl = wn*32 + ni*16 + r16;      // d within head
          const _Float16 hh = (_Float16)xnew;
          const _Float16 lo = (_Float16)(xnew - (float)hh);
          kh_t[nl*72 + dl] = hh;  kl_t[nl*72 + dl] = lo;
          lhv [dl*40 + nl] = hh;  llv [dl*40 + nl] = lo;
        }
      }
    }
  if (MODE == 1 && Kh){
    __syncthreads();
    const int bh2  = (by2>>5)*16 + bx2;     // batch*16 + head
    const int tseq = (by2>>1) & 15;         // 64-token KV tile
    const int half = by2 & 1;               // which 32-token half
    // K: 32 rows x 64 d, one f16x8 per thread per buffer
    const int n = tid>>3, c0q = (tid&7)*8;
    const size_t kbase = ((size_t)bh2*1024 + tseq*64 + half*32 + n)*64;
    const int swn = PHI(n)*8;    // PHI reads bits 3,1,0 only -> half-offset transparent
    *(f16x8*)&Kh[kbase + (c0q ^ swn)] = *(const f16x8*)&kh_t[n*72 + c0q];
    *(f16x8*)&Kl[kbase + (c0q ^ swn)] = *(const f16x8*)&kl_t[n*72 + c0q];
    // V: 64 d x 32 token-cols, one f16x8 per thread per buffer
    const int d = tid>>2, lb = (tid&3)*8;
    const size_t vbase = ((size_t)bh2*64 + d)*1024 + tseq*64;
    const int sw2 = (d&7)*8;
    const int colw = (half*32 + lb) ^ sw2;   // 8-aligned (sw2 only touches bits 3..5)
    *(f16x8*)&Vh[vbase + colw] = *(const f16x8*)&lhv[d*40 + lb];
    *(f16x8*)&Vl[vbase + colw] = *(const f16x8*)&llv[d*40 + lb];
  }
}

extern "C" void kernel_launch(void* const* d_in, const int* in_sizes, int n_in,
                              void* d_out, int out_size, void* d_ws, size_t ws_size,
                              hipStream_t stream){
  const float* x_in = (const float*)d_in[0];
  const float* ln_g = (const float*)d_in[1];
  const float* ln_b = (const float*)d_in[2];
  const float* w1   = (const float*)d_in[3];
  const float* w2   = (const float*)d_in[4];
  const float* fg   = (const float*)d_in[5];
  const float* fb   = (const float*)d_in[6];

  char* ws = (char*)d_ws;
  double*   dsum  = (double*)ws;            // 12
  double*   dabs  = (double*)(ws + 96);     // 12
  _Float16* wb = (_Float16*)(ws + 256);     // 12 * 1M fp16 = 24 MB
  size_t o = 256 + 12ull*1048576ull*2ull;
  float* xA = (float*)(ws + o); o += 2048ull*1024*4;
  float* xB = (float*)(ws + o); o += 2048ull*1024*4;
  _Float16* Kh = (_Float16*)(ws + o); o += 2048ull*1024*2;
  _Float16* Kl = (_Float16*)(ws + o); o += 2048ull*1024*2;
  _Float16* Vh = (_Float16*)(ws + o); o += 2048ull*1024*2;
  _Float16* Vl = (_Float16*)(ws + o); o += 2048ull*1024*2;
  _Float16* Ahb = (_Float16*)(ws + o); o += 2048ull*1024*2;
  _Float16* Alb = (_Float16*)(ws + o); o += 2048ull*1024*2;
  _Float16* Ghb = (_Float16*)(ws + o); o += 2048ull*1024*2;
  _Float16* Glb = (_Float16*)(ws + o); o += 2048ull*1024*2;

  hipMemsetAsync(ws, 0, 256, stream);
  k_wstats  <<<dim3(32,12), 256, 0, stream>>>(w1, w2, dsum, dabs);
  k_binarize<<<6144,        256, 0, stream>>>(w1, w2, dsum, wb);
  k_presplit<<<dim3(16,32), 256, 0, stream>>>(x_in, Kh, Kl, Vh, Vl);

  const float* xc = x_in;
  for (int i = 0; i < 6; i++){
    float* xn = (i & 1) ? xB : xA;
    const bool last = (i == 5);
    k_attn    <<<dim3(32,16), 256, 0, stream>>>(Kh, Kl, Vh, Vl, xc, xn);
    k_ln<1>   <<<512, 256, 0, stream>>>(xn, ln_g + (size_t)i*1024, ln_b + (size_t)i*1024,
                                        nullptr, Ahb, Alb);
    k_gemm<0> <<<dim3(16,64), 256, 0, stream>>>(Ahb, Alb, wb + (size_t)i*1048576,
                                                nullptr, Ghb, Glb, &dabs[i],
                                                nullptr, nullptr, nullptr, nullptr);
    k_gemm<1> <<<dim3(16,64), 256, 0, stream>>>(Ghb, Glb, wb + (size_t)(6+i)*1048576,
                                                xn, nullptr, nullptr, &dabs[6+i],
                                                last ? nullptr : Kh, last ? nullptr : Kl,
                                                last ? nullptr : Vh, last ? nullptr : Vl);
    xc = xn;
  }
  k_ln<0><<<512, 256, 0, stream>>>(xc, fg, fb, (float*)d_out, nullptr, nullptr);
}

// Round 19
// 476.693 us; speedup vs baseline: 1.0984x; 1.0043x over previous
//
#include <hip/hip_runtime.h>
#include <math.h>

typedef __attribute__((ext_vector_type(4))) float f32x4;
typedef __attribute__((ext_vector_type(8))) _Float16 f16x8;

__device__ __forceinline__ f32x4 mfma16h(f16x8 a, f16x8 b, f32x4 c){
  return __builtin_amdgcn_mfma_f32_16x16x32_f16(a, b, c, 0, 0, 0);
}
__device__ __forceinline__ void gload_lds16(const void* g, void* l){
  __builtin_amdgcn_global_load_lds((const __attribute__((address_space(1))) void*)g,
                                   (__attribute__((address_space(3))) void*)l, 16, 0, 0);
}

#define EXPC 0.1803368801111204f   // 0.125 * log2(e)
// global K swizzle phi(n) = bits (n3,n1,n0): chosen so phi(kappa(p)) = p&7 ->
// attn K-read XOR is (r16&7)*8, sequential across lanes = conflict-free (r10-verified).
#define PHI(n) (((((n)>>3)&1)<<2) | ((((n)>>1)&1)<<1) | ((n)&1))

// ---------------- weight stats: alpha=mean(w), beta-sum=sum|w| ----------------
__global__ __launch_bounds__(256) void k_wstats(const float* __restrict__ w1, const float* __restrict__ w2,
                                                double* __restrict__ dsum, double* __restrict__ dabs){
  const int mat = blockIdx.y;
  const float* wp = (mat < 6) ? (w1 + (size_t)mat*1048576) : (w2 + (size_t)(mat-6)*1048576);
  const f32x4* wv = (const f32x4*)wp + (size_t)blockIdx.x*8192;
  double s = 0.0, a = 0.0;
  for (int j = 0; j < 32; j++){
    f32x4 v = wv[j*256 + threadIdx.x];
    s += (double)v.x + (double)v.y + (double)v.z + (double)v.w;
    a += (double)fabsf(v.x) + (double)fabsf(v.y) + (double)fabsf(v.z) + (double)fabsf(v.w);
  }
  for (int d = 1; d < 64; d <<= 1){ s += __shfl_xor(s, d); a += __shfl_xor(a, d); }
  __shared__ double red[8];
  const int w = threadIdx.x >> 6;
  if ((threadIdx.x & 63) == 0){ red[w*2] = s; red[w*2+1] = a; }
  __syncthreads();
  if (threadIdx.x == 0){
    double S = red[0]+red[2]+red[4]+red[6], A = red[1]+red[3]+red[5]+red[7];
    atomicAdd(&dsum[mat], S);
    atomicAdd(&dabs[mat], A);
  }
}

// ---------------- binarize weights to fp16 {-1,0,+1}, swizzled GEMM-B layout ----------------
// layout: wb[mat][n][ (k&~63) + ((k&63) ^ 8*(n&7)) ]
__global__ __launch_bounds__(256) void k_binarize(const float* __restrict__ w1, const float* __restrict__ w2,
                                                  const double* __restrict__ dsum, _Float16* __restrict__ wb){
  const int blk = blockIdx.x;          // 6144 blocks, 512 per matrix
  const int mat = blk >> 9;
  const float alpha = (float)(dsum[mat] * (1.0/1048576.0));
  const float* wp = (mat < 6) ? (w1 + (size_t)mat*1048576) : (w2 + (size_t)(mat-6)*1048576);
  const size_t off = (size_t)(blk & 511)*2048 + (size_t)threadIdx.x*8;
  const int n = (int)(off >> 10), k = (int)(off & 1023);
  f32x4 v0 = *(const f32x4*)(wp + off), v1 = *(const f32x4*)(wp + off + 4);
  float vv[8] = {v0.x,v0.y,v0.z,v0.w,v1.x,v1.y,v1.z,v1.w};
  f16x8 pk;
  #pragma unroll
  for (int e = 0; e < 8; e++){
    float d = vv[e] - alpha;
    pk[e] = d > 0.f ? (_Float16)1.0f : (d < 0.f ? (_Float16)(-1.0f) : (_Float16)0.0f);
  }
  const size_t addr = (size_t)mat*1048576 + (size_t)n*1024 + (size_t)((k & ~63) + ((k & 63) ^ ((n&7)*8)));
  *(f16x8*)&wb[addr] = pk;
}

// ---------------- presplit (layer 0 only): x -> fp16 hi/lo K-layout + V^T-layout ----------------
// K:  Kh/Kl[bh][n][ d ^ 8*PHI(n&63) ]
// VT: Vh/Vl[bh][d][ t*64 + ((n&63) ^ 8*(d&7)) ]
__global__ __launch_bounds__(256) void k_presplit(const float* __restrict__ x,
                                                  _Float16* __restrict__ Kh, _Float16* __restrict__ Kl,
                                                  _Float16* __restrict__ Vh, _Float16* __restrict__ Vl){
  __shared__ _Float16 lh[64*72], ll[64*72];
  const int t = blockIdx.x, bh = blockIdx.y, b = bh>>4, h = bh&15;
  const int n = threadIdx.x>>2, c0 = (threadIdx.x&3)*16;
  const float* src = x + (size_t)b*1048576 + (size_t)(t*64+n)*1024 + h*64 + c0;
  const size_t kbase = ((size_t)bh*1024 + t*64 + n)*64;
  const int sw = PHI(n)*8;
  #pragma unroll
  for (int j = 0; j < 2; j++){
    f32x4 v0 = *(const f32x4*)(src + j*8);
    f32x4 v1 = *(const f32x4*)(src + j*8 + 4);
    float vv[8] = {v0.x,v0.y,v0.z,v0.w,v1.x,v1.y,v1.z,v1.w};
    f16x8 Hv, Lv;
    #pragma unroll
    for (int e = 0; e < 8; e++){
      _Float16 hh = (_Float16)vv[e];
      Hv[e] = hh; Lv[e] = (_Float16)(vv[e] - (float)hh);
      const int d = c0 + j*8 + e;
      lh[d*72 + n] = Hv[e]; ll[d*72 + n] = Lv[e];
    }
    const int db = c0 + j*8;
    *(f16x8*)&Kh[kbase + (db ^ sw)] = Hv;
    *(f16x8*)&Kl[kbase + (db ^ sw)] = Lv;
  }
  __syncthreads();
  const int d = threadIdx.x>>2, n0c = (threadIdx.x&3)*16;
  const size_t vbase = ((size_t)bh*64 + d)*1024 + t*64;
  const int sw2 = (d&7)*8;
  #pragma unroll
  for (int j = 0; j < 2; j++){
    const int nb = n0c + j*8;
    *(f16x8*)&Vh[vbase + (nb ^ sw2)] = *(const f16x8*)&lh[d*72 + nb];
    *(f16x8*)&Vl[vbase + (nb ^ sw2)] = *(const f16x8*)&ll[d*72 + nb];
  }
}

// ---------------- flash attention + residual: swapped QK^T, S-pipeline (r12/r15) ----------------
// grid (32 bh, 16 qt), 256 thr, 2 blocks/CU. (flat%8 = bh%8 -> already XCD-local.)
__global__ __launch_bounds__(256) void k_attn(const _Float16* __restrict__ Kh, const _Float16* __restrict__ Kl,
                                              const _Float16* __restrict__ Vh, const _Float16* __restrict__ Vl,
                                              const float* __restrict__ xin, float* __restrict__ xout){
  __shared__ _Float16 smb[40960];   // 80 KB: K0,K1,K2 (8192 el each) + V0,V1 (8192 el each)
  const int tid = threadIdx.x, w = tid>>6, l = tid&63, g = l>>4, r16 = l&15;
  const int bh = blockIdx.x, qt = blockIdx.y, b = bh>>4, h = bh&15;
  const _Float16* Kbh = Kh + (size_t)bh*65536;
  const _Float16* Kbl = Kl + (size_t)bh*65536;

  size_t koffK[2], voff[2];
  int cbj[2];
  #pragma unroll
  for (int j = 0; j < 2; j++){
    const int cb = (j*4 + w)*64, c = cb + l;
    const int p  = c>>3;
    const int kp = (p&32) | ((p&12)<<1) | ((p&16)>>2) | (p&3);   // kappa(p)
    cbj[j]   = cb;
    koffK[j] = (size_t)kp*64 + (size_t)(l&7)*8;
    voff[j]  = ((size_t)bh*64 + (c>>3))*1024 + (size_t)(c&7)*8;
  }
  #define KSTAGE(PK, T) { _Pragma("unroll")                                          \
    for (int j = 0; j < 2; j++){                                                      \
      gload_lds16(Kbh + (size_t)(T)*4096 + koffK[j], (PK) + cbj[j]*8);                \
      gload_lds16(Kbl + (size_t)(T)*4096 + koffK[j], (PK) + 4096 + cbj[j]*8);         \
    } }
  #define VSTAGE(PV, T) { _Pragma("unroll")                                          \
    for (int j = 0; j < 2; j++){                                                      \
      gload_lds16(Vh + voff[j] + (T)*64, (PV) + cbj[j]*8);                            \
      gload_lds16(Vl + voff[j] + (T)*64, (PV) + 4096 + cbj[j]*8);                     \
    } }

  _Float16* pKo = smb;
  _Float16* pKn = smb + 8192;
  _Float16* pKs = smb + 16384;
  _Float16* pVc = smb + 24576;
  _Float16* pVs = smb + 32768;

  KSTAGE(pKo, 0); KSTAGE(pKn, 1); VSTAGE(pVc, 0);
  const int qrow = w*16 + r16;
  const int phq8 = PHI(qrow)*8;
  const size_t qb = (size_t)qt*4096 + (size_t)qrow*64;
  const f16x8 aqh0 = *(const f16x8*)&Kbh[qb + ((g*8) ^ phq8)];
  const f16x8 aqh1 = *(const f16x8*)&Kbh[qb + ((32 + g*8) ^ phq8)];
  const f16x8 aql0 = *(const f16x8*)&Kbl[qb + ((g*8) ^ phq8)];
  const f16x8 aql1 = *(const f16x8*)&Kbl[qb + ((32 + g*8) ^ phq8)];
  __syncthreads();

  const int swk8 = (r16&7)*8;
  float mI = -1e30f, lI = 0.f;
  f32x4 acc[4], sA[4], sB[4];
  #pragma unroll
  for (int i = 0; i < 4; i++) acc[i] = (f32x4){0.f,0.f,0.f,0.f};

  #define QKT(PK, SD) { const _Float16* kt_h = (PK); const _Float16* kt_l = (PK) + 4096;  \
    _Pragma("unroll")                                                                      \
    for (int c = 0; c < 4; c++){                                                           \
      const int rk = c*16 + r16;                                                           \
      const f16x8 kh0 = *(const f16x8*)&kt_h[rk*64 + ((g*8) ^ swk8)];                      \
      const f16x8 kh1 = *(const f16x8*)&kt_h[rk*64 + ((32+g*8) ^ swk8)];                   \
      const f16x8 kl0 = *(const f16x8*)&kt_l[rk*64 + ((g*8) ^ swk8)];                      \
      const f16x8 kl1 = *(const f16x8*)&kt_l[rk*64 + ((32+g*8) ^ swk8)];                   \
      f32x4 z = (f32x4){0.f,0.f,0.f,0.f};                                                  \
      z = mfma16h(kh0, aqh0, z);                                                           \
      z = mfma16h(kh1, aqh1, z);                                                           \
      z = mfma16h(kh0, aql0, z);                                                           \
      z = mfma16h(kh1, aql1, z);                                                           \
      z = mfma16h(kl0, aqh0, z);                                                           \
      z = mfma16h(kl1, aqh1, z);                                                           \
      (SD)[c] = z;                                                                         \
    } }

  #define SMAXPV(SC) {                                                                     \
    float rmax = (SC)[0][0];                                                               \
    _Pragma("unroll")                                                                      \
    for (int c = 0; c < 4; c++)                                                            \
      _Pragma("unroll")                                                                    \
      for (int i = 0; i < 4; i++) rmax = fmaxf(rmax, (SC)[c][i]);                          \
    rmax = fmaxf(rmax, __shfl_xor(rmax, 16));                                              \
    rmax = fmaxf(rmax, __shfl_xor(rmax, 32));                                              \
    if (__any(rmax - mI > 44.36f)){                                                        \
      const float mn = fmaxf(mI, rmax);                                                    \
      const float fac = exp2f((mI - mn)*EXPC);                                             \
      lI *= fac;                                                                           \
      mI = mn;                                                                             \
      _Pragma("unroll")                                                                    \
      for (int i = 0; i < 4; i++){                                                         \
        const float fi = __shfl(fac, g*4 + i);                                             \
        _Pragma("unroll")                                                                  \
        for (int dc = 0; dc < 4; dc++) acc[dc][i] *= fi;                                   \
      }                                                                                    \
    }                                                                                      \
    const float mC = mI*EXPC;                                                              \
    float rsum = 0.f;                                                                      \
    f16x8 aph[2], apl[2];                                                                  \
    _Pragma("unroll")                                                                      \
    for (int c = 0; c < 4; c++)                                                            \
      _Pragma("unroll")                                                                    \
      for (int i = 0; i < 4; i++){                                                         \
        const float p = exp2f(fmaf((SC)[c][i], EXPC, -mC));                                \
        const _Float16 ph = (_Float16)p;                                                   \
        aph[c>>1][(c&1)*4 + i] = ph;                                                       \
        apl[c>>1][(c&1)*4 + i] = (_Float16)(p - (float)ph);                                \
        rsum += p;                                                                         \
      }                                                                                    \
    rsum += __shfl_xor(rsum, 16);                                                          \
    rsum += __shfl_xor(rsum, 32);                                                          \
    lI += rsum;                                                                            \
    const _Float16* vt_h = pVc; const _Float16* vt_l = pVc + 4096;                         \
    _Pragma("unroll")                                                                      \
    for (int ks = 0; ks < 2; ks++){                                                        \
      _Pragma("unroll")                                                                    \
      for (int dc = 0; dc < 4; dc++){                                                      \
        const int vr = dc*16 + r16;                                                        \
        const f16x8 bvh = *(const f16x8*)&vt_h[vr*64 + ((ks*32 + g*8) ^ swk8)];            \
        const f16x8 bvl = *(const f16x8*)&vt_l[vr*64 + ((ks*32 + g*8) ^ swk8)];            \
        acc[dc] = mfma16h(aph[ks], bvh, acc[dc]);                                          \
        acc[dc] = mfma16h(apl[ks], bvh, acc[dc]);                                          \
        acc[dc] = mfma16h(aph[ks], bvl, acc[dc]);                                          \
      }                                                                                    \
    } }

  QKT(pKo, sA);

  for (int tt = 0; tt < 8; tt++){
    {
      const int t = 2*tt;
      if (t < 14) KSTAGE(pKs, t+2);
      VSTAGE(pVs, t+1);
      QKT(pKn, sB);
      SMAXPV(sA);
      __syncthreads();
      _Float16* tk = pKo; pKo = pKn; pKn = pKs; pKs = tk;
      _Float16* tv = pVc; pVc = pVs; pVs = tv;
    }
    {
      const int t = 2*tt+1;
      if (t < 14) KSTAGE(pKs, t+2);
      if (t < 15) VSTAGE(pVs, t+1);
      if (t < 15) QKT(pKn, sA);
      SMAXPV(sB);
      __syncthreads();
      _Float16* tk = pKo; pKo = pKn; pKn = pKs; pKs = tk;
      _Float16* tv = pVc; pVc = pVs; pVs = tv;
    }
  }
  #undef KSTAGE
  #undef VSTAGE
  #undef QKT
  #undef SMAXPV

  #pragma unroll
  for (int i = 0; i < 4; i++){
    const float li = __shfl(lI, g*4 + i);
    const float inv = 1.f/li;
    const int row = qt*64 + w*16 + g*4 + i;
    #pragma unroll
    for (int dc = 0; dc < 4; dc++){
      const size_t idx = (size_t)b*1048576 + (size_t)row*1024 + h*64 + dc*16 + r16;
      xout[idx] = acc[dc][i]*inv + xin[idx];
    }
  }
}

// ---------------- layernorm; SPLIT=1 writes fp16 hi/lo in swizzled A-layout ----------------
template<int SPLIT>
__global__ __launch_bounds__(256) void k_ln(const float* __restrict__ x, const float* __restrict__ gg,
                                            const float* __restrict__ bb, float* __restrict__ outf,
                                            _Float16* __restrict__ Oh, _Float16* __restrict__ Ol){
  const int row = blockIdx.x*4 + (threadIdx.x>>6);
  const int lane = threadIdx.x & 63;
  const float* xr = x + (size_t)row*1024;
  f32x4 v[4];
  float s = 0.f, q = 0.f;
  #pragma unroll
  for (int c = 0; c < 2; c++){
    v[c*2]   = *(const f32x4*)(xr + c*512 + lane*8);
    v[c*2+1] = *(const f32x4*)(xr + c*512 + lane*8 + 4);
    #pragma unroll
    for (int e = 0; e < 4; e++){
      s += v[c*2][e] + v[c*2+1][e];
      q += v[c*2][e]*v[c*2][e] + v[c*2+1][e]*v[c*2+1][e];
    }
  }
  for (int d = 1; d < 64; d <<= 1){ s += __shfl_xor(s,d); q += __shfl_xor(q,d); }
  const float mean = s * (1.f/1024.f);
  const float var  = q * (1.f/1024.f) - mean*mean;
  const float rstd = rsqrtf(var + 1e-5f);
  #pragma unroll
  for (int c = 0; c < 2; c++){
    const int col = c*512 + lane*8;
    f32x4 g0 = *(const f32x4*)(gg + col), g1 = *(const f32x4*)(gg + col + 4);
    f32x4 b0 = *(const f32x4*)(bb + col), b1 = *(const f32x4*)(bb + col + 4);
    float h[8];
    #pragma unroll
    for (int e = 0; e < 4; e++){
      h[e]   = (v[c*2][e]  -mean)*rstd*g0[e] + b0[e];
      h[e+4] = (v[c*2+1][e]-mean)*rstd*g1[e] + b1[e];
    }
    if (SPLIT){
      f16x8 Hv, Lv;
      #pragma unroll
      for (int e = 0; e < 8; e++){
        _Float16 hh = (_Float16)h[e];
        Hv[e] = hh; Lv[e] = (_Float16)(h[e] - (float)hh);
      }
      const size_t addr = (size_t)row*1024 + c*512 + (lane>>3)*64 + (((lane&7)*8) ^ ((row&7)*8));
      *(f16x8*)&Oh[addr] = Hv;
      *(f16x8*)&Ol[addr] = Lv;
    } else {
      f32x4 o0, o1;
      #pragma unroll
      for (int e = 0; e < 4; e++){ o0[e] = h[e]; o1[e] = h[e+4]; }
      *(f32x4*)(outf + (size_t)row*1024 + col) = o0;
      *(f32x4*)(outf + (size_t)row*1024 + col + 4) = o1;
    }
  }
}

// ---------------- bitlinear GEMM: C[2048,1024] = (Ah+Al).Wb^T * beta ----------------
// BM=32, BN=64, BK=64, grid (16,64) = 1024 blocks = 4 blocks/CU. r15 schedule (best).
// T1 XCD swizzle: flat launch id -> nf = (flat&7)*128 + (flat>>3), so each XCD owns a
// contiguous 8-row-tile band: per-XCD L2 footprint = 1MB A-slice + 2MB W = 3MB <= 4MB
// (default x-major round-robin made every XCD touch all 8MB of A -> L2 thrash to L3).
// Bijective (1024 = 8*128) -> output bit-identical.
// MODE 0: GELU -> split fp16 out (swizzled A-layout).
// MODE 1: += into fp32 residual; if Kh!=null, ALSO produce next layer's K/V splits
//         (block == half of a presplit unit: tseq=by2>>1&15, half=by2&1, head=bx2).
template<int MODE>
__global__ __launch_bounds__(256) void k_gemm(const _Float16* __restrict__ Ah, const _Float16* __restrict__ Al,
                                              const _Float16* __restrict__ Wg,
                                              float* __restrict__ out32,
                                              _Float16* __restrict__ Oh, _Float16* __restrict__ Ol,
                                              const double* __restrict__ dabs_slot,
                                              _Float16* __restrict__ Kh, _Float16* __restrict__ Kl,
                                              _Float16* __restrict__ Vh, _Float16* __restrict__ Vl){
  __shared__ _Float16 smb[16384];   // 32KB: 2 x (A-hi 2048 + A-lo 2048 + B 4096); reused post-loop
  const int tid = threadIdx.x, w = tid>>6, l = tid&63, g = l>>4, r16 = l&15;
  const int wm = w>>1, wn = w&1;
  const int flat = blockIdx.y*16 + blockIdx.x;        // launch-order id (x-major)
  const int nf   = (flat & 7)*128 + (flat >> 3);      // XCD-contiguous remap (bijective)
  const int bx2  = nf & 15, by2 = nf >> 4;
  const int n0 = bx2*64, m0 = by2*32;
  const float scale = (float)(*dabs_slot * (1.0/1048576.0));
  const int swr = (r16&7)*8;
  f32x4 acc[2] = {};
  // staging: A-hi 4KB (wave w -> rows w*8..+7), A-lo 4KB, B 8KB (chunks j*4+w)
  #define STAGE(buf, k0) { _Float16* Bp = smb + (buf)*8192;                               \
    gload_lds16(Ah + (size_t)(m0 + w*8 + (l>>3))*1024 + (k0) + (l&7)*8, Bp + w*512);      \
    gload_lds16(Al + (size_t)(m0 + w*8 + (l>>3))*1024 + (k0) + (l&7)*8, Bp + 2048 + w*512);\
    _Pragma("unroll")                                                                     \
    for (int j = 0; j < 2; j++){                                                          \
      const int ch = j*4 + w;                                                             \
      gload_lds16(Wg + (size_t)(n0 + ch*8 + (l>>3))*1024 + (k0) + (l&7)*8,                \
                  Bp + 4096 + ch*512);                                                    \
    } }
  STAGE(0, 0);
  __syncthreads();
  for (int t = 0; t < 16; t++){
    if (t < 15) STAGE((t+1)&1, (t+1)*64);
    const _Float16* Bp = smb + (t&1)*8192;
    #pragma unroll
    for (int kk = 0; kk < 2; kk++){
      const int col = (kk*32 + g*8) ^ swr;
      const int arow = wm*16 + r16;
      const f16x8 ah = *(const f16x8*)&Bp[arow*64 + col];
      const f16x8 al = *(const f16x8*)&Bp[2048 + arow*64 + col];
      const f16x8 bf0 = *(const f16x8*)&Bp[4096 + (wn*32 + r16)*64 + col];
      const f16x8 bf1 = *(const f16x8*)&Bp[4096 + (wn*32 + 16 + r16)*64 + col];
      acc[0] = mfma16h(ah, bf0, acc[0]);
      acc[0] = mfma16h(al, bf0, acc[0]);
      acc[1] = mfma16h(ah, bf1, acc[1]);
      acc[1] = mfma16h(al, bf1, acc[1]);
    }
    __syncthreads();
  }
  #undef STAGE
  // post-loop LDS reuse (all waves past final barrier): split-tile staging for fused KV
  _Float16* kh_t = smb;            // [32][72] token-major hi
  _Float16* kl_t = smb + 2304;     // [32][72] token-major lo
  _Float16* lhv  = smb + 4608;     // [64][40] d-major hi (32 token cols)
  _Float16* llv  = smb + 7168;     // [64][40] d-major lo
  #pragma unroll
  for (int ni = 0; ni < 2; ni++)
    #pragma unroll
    for (int i = 0; i < 4; i++){
      const int rr = m0 + wm*16 + g*4 + i;
      const int cc = n0 + wn*32 + ni*16 + r16;
      float vv = acc[ni][i] * scale;
      if (MODE == 0){
        vv = 0.5f*vv*(1.f + erff(vv*0.70710678118f));
        _Float16 hh = (_Float16)vv;
        const size_t addr = (size_t)rr*1024 + (cc & ~63) + ((cc & 63) ^ ((rr&7)*8));
        Oh[addr] = hh;
        Ol[addr] = (_Float16)(vv - (float)hh);
      } else {
        const size_t idx = (size_t)rr*1024 + cc;
        const float xnew = out32[idx] + vv;
        out32[idx] = xnew;
        if (Kh){
          const int nl = wm*16 + g*4 + i;          // token within 32-tile
          const int dl = wn*32 + ni*16 + r16;      // d within head
          const _Float16 hh = (_Float16)xnew;
          const _Float16 lo = (_Float16)(xnew - (float)hh);
          kh_t[nl*72 + dl] = hh;  kl_t[nl*72 + dl] = lo;
          lhv [dl*40 + nl] = hh;  llv [dl*40 + nl] = lo;
        }
      }
    }
  if (MODE == 1 && Kh){
    __syncthreads();
    const int bh2  = (by2>>5)*16 + bx2;     // batch*16 + head
    const int tseq = (by2>>1) & 15;         // 64-token KV tile
    const int half = by2 & 1;               // which 32-token half
    // K: 32 rows x 64 d, one f16x8 per thread per buffer
    const int n = tid>>3, c0q = (tid&7)*8;
    const size_t kbase = ((size_t)bh2*1024 + tseq*64 + half*32 + n)*64;
    const int swn = PHI(n)*8;    // PHI reads bits 3,1,0 only -> half-offset transparent
    *(f16x8*)&Kh[kbase + (c0q ^ swn)] = *(const f16x8*)&kh_t[n*72 + c0q];
    *(f16x8*)&Kl[kbase + (c0q ^ swn)] = *(const f16x8*)&kl_t[n*72 + c0q];
    // V: 64 d x 32 token-cols, one f16x8 per thread per buffer
    const int d = tid>>2, lb = (tid&3)*8;
    const size_t vbase = ((size_t)bh2*64 + d)*1024 + tseq*64;
    const int sw2 = (d&7)*8;
    const int colw = (half*32 + lb) ^ sw2;   // 8-aligned (sw2 only touches bits 3..5)
    *(f16x8*)&Vh[vbase + colw] = *(const f16x8*)&lhv[d*40 + lb];
    *(f16x8*)&Vl[vbase + colw] = *(const f16x8*)&llv[d*40 + lb];
  }
}

extern "C" void kernel_launch(void* const* d_in, const int* in_sizes, int n_in,
                              void* d_out, int out_size, void* d_ws, size_t ws_size,
                              hipStream_t stream){
  const float* x_in = (const float*)d_in[0];
  const float* ln_g = (const float*)d_in[1];
  const float* ln_b = (const float*)d_in[2];
  const float* w1   = (const float*)d_in[3];
  const float* w2   = (const float*)d_in[4];
  const float* fg   = (const float*)d_in[5];
  const float* fb   = (const float*)d_in[6];

  char* ws = (char*)d_ws;
  double*   dsum  = (double*)ws;            // 12
  double*   dabs  = (double*)(ws + 96);     // 12
  _Float16* wb = (_Float16*)(ws + 256);     // 12 * 1M fp16 = 24 MB
  size_t o = 256 + 12ull*1048576ull*2ull;
  float* xA = (float*)(ws + o); o += 2048ull*1024*4;
  float* xB = (float*)(ws + o); o += 2048ull*1024*4;
  _Float16* Kh = (_Float16*)(ws + o); o += 2048ull*1024*2;
  _Float16* Kl = (_Float16*)(ws + o); o += 2048ull*1024*2;
  _Float16* Vh = (_Float16*)(ws + o); o += 2048ull*1024*2;
  _Float16* Vl = (_Float16*)(ws + o); o += 2048ull*1024*2;
  _Float16* Ahb = (_Float16*)(ws + o); o += 2048ull*1024*2;
  _Float16* Alb = (_Float16*)(ws + o); o += 2048ull*1024*2;
  _Float16* Ghb = (_Float16*)(ws + o); o += 2048ull*1024*2;
  _Float16* Glb = (_Float16*)(ws + o); o += 2048ull*1024*2;

  hipMemsetAsync(ws, 0, 256, stream);
  k_wstats  <<<dim3(32,12), 256, 0, stream>>>(w1, w2, dsum, dabs);
  k_binarize<<<6144,        256, 0, stream>>>(w1, w2, dsum, wb);
  k_presplit<<<dim3(16,32), 256, 0, stream>>>(x_in, Kh, Kl, Vh, Vl);

  const float* xc = x_in;
  for (int i = 0; i < 6; i++){
    float* xn = (i & 1) ? xB : xA;
    const bool last = (i == 5);
    k_attn    <<<dim3(32,16), 256, 0, stream>>>(Kh, Kl, Vh, Vl, xc, xn);
    k_ln<1>   <<<512, 256, 0, stream>>>(xn, ln_g + (size_t)i*1024, ln_b + (size_t)i*1024,
                                        nullptr, Ahb, Alb);
    k_gemm<0> <<<dim3(16,64), 256, 0, stream>>>(Ahb, Alb, wb + (size_t)i*1048576,
                                                nullptr, Ghb, Glb, &dabs[i],
                                                nullptr, nullptr, nullptr, nullptr);
    k_gemm<1> <<<dim3(16,64), 256, 0, stream>>>(Ghb, Glb, wb + (size_t)(6+i)*1048576,
                                                xn, nullptr, nullptr, &dabs[6+i],
                                                last ? nullptr : Kh, last ? nullptr : Kl,
                                                last ? nullptr : Vh, last ? nullptr : Vl);
    xc = xn;
  }
  k_ln<0><<<512, 256, 0, stream>>>(xc, fg, fb, (float*)d_out, nullptr, nullptr);
}